// Round 1
// baseline (4295.397 us; speedup 1.0000x reference)
//
#include <hip/hip_runtime.h>
#include <hip/hip_bf16.h>
#include <math.h>

// Problem constants
#define BB   8
#define NTOK 1024
#define DIM  768
#define DFF  3072
#define NP1  1025

// ---------------- reductions (wave = 64) ----------------
__device__ __forceinline__ float waveMax(float v){
  #pragma unroll
  for (int o = 32; o > 0; o >>= 1) v = fmaxf(v, __shfl_down(v, o, 64));
  return v;
}
__device__ __forceinline__ float waveSum(float v){
  #pragma unroll
  for (int o = 32; o > 0; o >>= 1) v += __shfl_down(v, o, 64);
  return v;
}
// 256-thread block reductions; result broadcast to all threads
__device__ __forceinline__ float blockMax(float v, float* red){
  int lane = threadIdx.x & 63, w = threadIdx.x >> 6;
  v = waveMax(v);
  if (lane == 0) red[w] = v;
  __syncthreads();
  float r = fmaxf(fmaxf(red[0], red[1]), fmaxf(red[2], red[3]));
  __syncthreads();
  return r;
}
__device__ __forceinline__ float blockSum(float v, float* red){
  int lane = threadIdx.x & 63, w = threadIdx.x >> 6;
  v = waveSum(v);
  if (lane == 0) red[w] = v;
  __syncthreads();
  float r = red[0] + red[1] + red[2] + red[3];
  __syncthreads();
  return r;
}

// ---------------- pos softmax: pos[i,j] = softmax_j(-|p_temp| * coords[i,j,:]·pe[i,:]) ----
__global__ __launch_bounds__(256) void pos_kernel(
    const float* __restrict__ coords, const float* __restrict__ pos_emb,
    const float* __restrict__ p_temp, float* __restrict__ pos)
{
  int i = blockIdx.x;
  int tid = threadIdx.x;
  __shared__ float red[4];
  __shared__ float pe[6];
  if (tid < 6) pe[tid] = pos_emb[i*6 + tid];
  __syncthreads();
  float pt = fabsf(p_temp[0]);
  float v[4]; float mx = -INFINITY;
  #pragma unroll
  for (int j = 0; j < 4; j++){
    int jj = tid + j*256;
    const float* c = coords + ((long long)i*NTOK + jj)*6;
    float d = c[0]*pe[0] + c[1]*pe[1] + c[2]*pe[2] + c[3]*pe[3] + c[4]*pe[4] + c[5]*pe[5];
    v[j] = -pt * d;
    mx = fmaxf(mx, v[j]);
  }
  mx = blockMax(mx, red);
  float s = 0.f;
  #pragma unroll
  for (int j = 0; j < 4; j++){ v[j] = __expf(v[j] - mx); s += v[j]; }
  s = blockSum(s, red);
  float inv = 1.f / s;
  #pragma unroll
  for (int j = 0; j < 4; j++) pos[(long long)i*NTOK + tid + j*256] = v[j] * inv;
}

// ------- per-row: softmax(S) -> attn -> entropy -> select k -> write attn_c into S[b,0,i,:] ----
__global__ __launch_bounds__(256) void rowproc_kernel(
    float* __restrict__ S,          // (B,2,N,N) logits in, attn_c out (k=0 slice)
    const float* __restrict__ pos,  // (N,N)
    float* __restrict__ heat,       // (B,N)
    const float* __restrict__ gating, const float* __restrict__ h_temp)
{
  int row = blockIdx.x;           // b*N + i
  int b = row >> 10, i = row & 1023;
  int tid = threadIdx.x;
  __shared__ float a0[NTOK];
  __shared__ float a1[NTOK];
  __shared__ float red[4];
  float g = 1.f / (1.f + __expf(-gating[0]));
  float ht = h_temp[0];
  float ent[2];
  #pragma unroll
  for (int k = 0; k < 2; k++){
    const float* Sr = S + ((long long)((b*2 + k)*NTOK) + i) * NTOK;
    float v[4]; float mx = -INFINITY;
    #pragma unroll
    for (int j = 0; j < 4; j++){ v[j] = Sr[tid + j*256]; mx = fmaxf(mx, v[j]); }
    mx = blockMax(mx, red);
    float s = 0.f;
    #pragma unroll
    for (int j = 0; j < 4; j++){ v[j] = __expf(v[j] - mx); s += v[j]; }
    s = blockSum(s, red);
    float inv = 1.f / s;
    float e = 0.f;
    float* arow = k ? a1 : a0;
    #pragma unroll
    for (int j = 0; j < 4; j++){
      float p = v[j] * inv;
      float at = (1.f - g) * p + g * pos[(long long)i*NTOK + tid + j*256];
      arow[tid + j*256] = at;
      e += -at * __logf(at + 1e-8f);
    }
    ent[k] = blockSum(e, red);
  }
  float h0 = 2.f - 2.f / (1.f + __expf(-ht * ent[0]));
  float h1 = 2.f - 2.f / (1.f + __expf(-ht * ent[1]));
  bool fg = (h0 >= h1);
  if (tid == 0) heat[row] = fg ? h0 : h1;
  const float* sel = fg ? a0 : a1;
  float* out = S + ((long long)((b*2 + 0)*NTOK) + i) * NTOK;
  #pragma unroll
  for (int j = 0; j < 4; j++) out[tid + j*256] = sel[tid + j*256];
}

// ---------------- copy CLS row of y into y_full ----------------
__global__ void cls_copy_kernel(const float* __restrict__ y, float* __restrict__ yfull){
  int idx = blockIdx.x*256 + threadIdx.x;
  if (idx < BB*DIM){
    int b = idx / DIM, d = idx % DIM;
    yfull[(long long)b*NP1*DIM + d] = y[(long long)b*NP1*DIM + d];
  }
}

// ---------------- generic batched fp32 GEMM ----------------
// C[z][m][n] (+)= alpha * sum_k f(A[z][m][k]) * B[z>>shiftB][.,.] (+ bias[n]) (+heat epilogue)
// TRANSB==0: B[k][n] row-major ldb ; TRANSB==1: B[n][k] row-major ldb
template<int TRANSB>
__global__ __launch_bounds__(256) void sgemm_kernel(
    const float* __restrict__ A, const float* __restrict__ Bm, float* __restrict__ C,
    int M, int Nc, int K,
    int lda, int ldb, int ldc,
    long long strideAz, long long strideBz, long long strideCz,
    int shiftB, float alpha,
    const float* __restrict__ ascale,  // per-k |ascale[k]| applied to A (nullable)
    int geluA, int accumulate,
    const float* __restrict__ bias,    // per-n (nullable)
    const float* __restrict__ xadd,    // residual, same layout as C (nullable)
    const float* __restrict__ heat,    // (z, M-1) row scaling; row 0 unscaled
    int heatMode)
{
  const int BM = 64, BN = 64, BK = 16;
  __shared__ float As[BK][BM + 1];
  __shared__ float Bs[BK][BN + 1];
  int tid = threadIdx.x;
  int n0 = blockIdx.x * BN, m0 = blockIdx.y * BM;
  int z = blockIdx.z;
  const float* Ab = A + (long long)z * strideAz;
  const float* Bb = Bm + (long long)(z >> shiftB) * strideBz;
  float* Cb = C + (long long)z * strideCz;
  int tx = tid & 15, ty = tid >> 4;
  float acc[4][4] = {};

  for (int k0 = 0; k0 < K; k0 += BK){
    // A tile: 64 rows x 16 k, 16 rows per pass
    #pragma unroll
    for (int p = 0; p < 4; p++){
      int m = (tid >> 4) + p*16;
      int k = tid & 15;
      int gm = m0 + m, gk = k0 + k;
      float v = 0.f;
      if (gm < M) v = Ab[(long long)gm * lda + gk];
      if (ascale) v *= fabsf(ascale[gk]);
      if (geluA)  v = 0.5f * v * (1.f + erff(v * 0.70710678118654752f));
      As[k][m] = v;
    }
    // B tile
    if (TRANSB == 0){
      #pragma unroll
      for (int p = 0; p < 4; p++){
        int k = (tid >> 6) + p*4;
        int n = tid & 63;
        Bs[k][n] = Bb[(long long)(k0 + k) * ldb + (n0 + n)];
      }
    } else {
      #pragma unroll
      for (int p = 0; p < 4; p++){
        int n = (tid >> 4) + p*16;
        int k = tid & 15;
        Bs[k][n] = Bb[(long long)(n0 + n) * ldb + (k0 + k)];
      }
    }
    __syncthreads();
    #pragma unroll
    for (int kk = 0; kk < BK; kk++){
      float a[4], bvals[4];
      #pragma unroll
      for (int i = 0; i < 4; i++) a[i] = As[kk][ty*4 + i];
      #pragma unroll
      for (int j = 0; j < 4; j++) bvals[j] = Bs[kk][tx*4 + j];
      #pragma unroll
      for (int i = 0; i < 4; i++)
        #pragma unroll
        for (int j = 0; j < 4; j++)
          acc[i][j] += a[i] * bvals[j];
    }
    __syncthreads();
  }

  #pragma unroll
  for (int i = 0; i < 4; i++){
    int gm = m0 + ty*4 + i;
    if (gm >= M) continue;
    #pragma unroll
    for (int j = 0; j < 4; j++){
      int gn = n0 + tx*4 + j;
      float c = alpha * acc[i][j];
      if (bias) c += bias[gn];
      long long cidx = (long long)gm * ldc + gn;
      if (accumulate) c += Cb[cidx];
      if (heatMode){
        float f = (gm == 0) ? 1.f : heat[(long long)z * NTOK + (gm - 1)];
        c = xadd[(long long)z * strideCz + cidx] + f * c;
      }
      Cb[cidx] = c;
    }
  }
}

extern "C" void kernel_launch(void* const* d_in, const int* in_sizes, int n_in,
                              void* d_out, int out_size, void* d_ws, size_t ws_size,
                              hipStream_t stream)
{
  const float* x       = (const float*)d_in[0];
  const float* y       = (const float*)d_in[1];
  const float* coords  = (const float*)d_in[2];
  const float* U       = (const float*)d_in[3];
  const float* S1      = (const float*)d_in[4];
  const float* S2      = (const float*)d_in[5];
  const float* gating  = (const float*)d_in[6];
  const float* h_temp  = (const float*)d_in[7];
  const float* p_temp  = (const float*)d_in[8];
  const float* pos_emb = (const float*)d_in[9];
  const float* W1      = (const float*)d_in[10];
  const float* b1      = (const float*)d_in[11];
  const float* W2      = (const float*)d_in[12];
  const float* b2      = (const float*)d_in[13];
  float* out = (float*)d_out;
  float* ws  = (float*)d_ws;

  // workspace layout (floats), with lifetime-based overlays:
  //   pos  [0, N*N)
  //   big region: xs (2*B*N*D) ++ S (B*2*N*N); t lives inside S slot (steps 2-3);
  //               h (B*NP1*DFF) overlays the whole big region (steps 7-8)
  //   heat, yfull after.
  const long long NN   = (long long)NTOK * NTOK;          // 1,048,576
  const long long BND  = (long long)BB * NTOK * DIM;      // 6,291,456
  const long long o_pos   = 0;
  const long long o_big   = o_pos + NN;
  const long long o_xs    = o_big;                        // 2*BND floats
  const long long o_S     = o_xs + 2*BND;                 // 16*NN floats
  const long long o_t     = o_S;                          // t inside S slot
  const long long o_h     = o_big;                        // h overlays xs+S
  const long long bigsz   = 2*BND + 16*NN;                // 29,360,128
  const long long o_heat  = o_big + bigsz;
  const long long o_yfull = o_heat + (long long)BB*NTOK;

  const float scale = 0.03608439182435161f; // 768^-0.5
  dim3 blk(256);

  // 1) pos softmax
  pos_kernel<<<dim3(NTOK), blk, 0, stream>>>(coords, pos_emb, p_temp, ws + o_pos);

  // 2) t = xb @ U^T   (batched over b, M=1024, N=768, K=768)
  sgemm_kernel<1><<<dim3(12,16,BB), blk, 0, stream>>>(
      x + DIM, U, ws + o_t,
      NTOK, DIM, DIM, DIM, DIM, DIM,
      (long long)NP1*DIM, 0LL, (long long)NTOK*DIM,
      0, 1.f, nullptr, 0, 0, nullptr, nullptr, nullptr, 0);

  // 3) xs_k = (t*|Sk|) @ U  (two launches, batched over b)
  sgemm_kernel<0><<<dim3(12,16,BB), blk, 0, stream>>>(
      ws + o_t, U, ws + o_xs,
      NTOK, DIM, DIM, DIM, DIM, DIM,
      (long long)NTOK*DIM, 0LL, 2LL*NTOK*DIM,
      0, 1.f, S1, 0, 0, nullptr, nullptr, nullptr, 0);
  sgemm_kernel<0><<<dim3(12,16,BB), blk, 0, stream>>>(
      ws + o_t, U, ws + o_xs + (long long)NTOK*DIM,
      NTOK, DIM, DIM, DIM, DIM, DIM,
      (long long)NTOK*DIM, 0LL, 2LL*NTOK*DIM,
      0, 1.f, S2, 0, 0, nullptr, nullptr, nullptr, 0);

  // 4) S[z=(b*2+k)] = scale * xs[z] @ yb[b]^T   (z=16, M=N=1024, K=768)
  sgemm_kernel<1><<<dim3(16,16,16), blk, 0, stream>>>(
      ws + o_xs, y + DIM, ws + o_S,
      NTOK, NTOK, DIM, DIM, DIM, NTOK,
      (long long)NTOK*DIM, (long long)NP1*DIM, NN,
      1, scale, nullptr, 0, 0, nullptr, nullptr, nullptr, 0);

  // 5) per-row: softmax + mix pos + entropy + select -> attn_c into S[b,0,:,:], heat
  rowproc_kernel<<<dim3(BB*NTOK), blk, 0, stream>>>(
      ws + o_S, ws + o_pos, ws + o_heat, gating, h_temp);

  // 6) y_out = attn_c @ yb  -> yfull rows 1..N ; plus CLS copy
  sgemm_kernel<0><<<dim3(12,16,BB), blk, 0, stream>>>(
      ws + o_S, y + DIM, ws + o_yfull + DIM,
      NTOK, DIM, NTOK, NTOK, DIM, DIM,
      2LL*NN, (long long)NP1*DIM, (long long)NP1*DIM,
      0, 1.f, nullptr, 0, 0, nullptr, nullptr, nullptr, 0);
  cls_copy_kernel<<<dim3((BB*DIM + 255)/256), blk, 0, stream>>>(y, ws + o_yfull);

  // 7) h = x @ W1[:768] + yfull @ W1[768:] + b1   (M=1025, N=3072)
  sgemm_kernel<0><<<dim3(48,17,BB), blk, 0, stream>>>(
      x, W1, ws + o_h,
      NP1, DFF, DIM, DIM, DFF, DFF,
      (long long)NP1*DIM, 0LL, (long long)NP1*DFF,
      0, 1.f, nullptr, 0, 0, b1, nullptr, nullptr, 0);
  sgemm_kernel<0><<<dim3(48,17,BB), blk, 0, stream>>>(
      ws + o_yfull, W1 + (long long)DIM*DFF, ws + o_h,
      NP1, DFF, DIM, DIM, DFF, DFF,
      (long long)NP1*DIM, 0LL, (long long)NP1*DFF,
      0, 1.f, nullptr, 0, 1, nullptr, nullptr, nullptr, 0);

  // 8) out = x + rowscale(gelu(h) @ W2 + b2)   (M=1025, N=768, K=3072)
  sgemm_kernel<0><<<dim3(12,17,BB), blk, 0, stream>>>(
      ws + o_h, W2, out,
      NP1, DIM, DFF, DFF, DIM, DIM,
      (long long)NP1*DFF, 0LL, (long long)NP1*DIM,
      0, 1.f, nullptr, 1, 0, b2, x, ws + o_heat, 1);
}

// Round 2
// 667.045 us; speedup vs baseline: 6.4394x; 6.4394x over previous
//
#include <hip/hip_runtime.h>
#include <hip/hip_bf16.h>
#include <math.h>

#define BB   8
#define NTOK 1024
#define DIM  768
#define DFF  3072
#define NP1  1025

typedef __bf16 bf16x8 __attribute__((ext_vector_type(8)));
typedef float  f32x4  __attribute__((ext_vector_type(4)));

// ---------------- reductions (wave = 64) ----------------
__device__ __forceinline__ float waveMax(float v){
  #pragma unroll
  for (int o = 32; o > 0; o >>= 1) v = fmaxf(v, __shfl_down(v, o, 64));
  return v;
}
__device__ __forceinline__ float waveSum(float v){
  #pragma unroll
  for (int o = 32; o > 0; o >>= 1) v += __shfl_down(v, o, 64);
  return v;
}
__device__ __forceinline__ float blockMax(float v, float* red){
  int lane = threadIdx.x & 63, w = threadIdx.x >> 6;
  v = waveMax(v);
  if (lane == 0) red[w] = v;
  __syncthreads();
  float r = fmaxf(fmaxf(red[0], red[1]), fmaxf(red[2], red[3]));
  __syncthreads();
  return r;
}
__device__ __forceinline__ float blockSum(float v, float* red){
  int lane = threadIdx.x & 63, w = threadIdx.x >> 6;
  v = waveSum(v);
  if (lane == 0) red[w] = v;
  __syncthreads();
  float r = red[0] + red[1] + red[2] + red[3];
  __syncthreads();
  return r;
}

// ---------------- pos softmax ----------------
__global__ __launch_bounds__(256) void pos_kernel(
    const float* __restrict__ coords, const float* __restrict__ pos_emb,
    const float* __restrict__ p_temp, float* __restrict__ pos)
{
  int i = blockIdx.x;
  int tid = threadIdx.x;
  __shared__ float red[4];
  __shared__ float pe[6];
  if (tid < 6) pe[tid] = pos_emb[i*6 + tid];
  __syncthreads();
  float pt = fabsf(p_temp[0]);
  float v[4]; float mx = -INFINITY;
  #pragma unroll
  for (int j = 0; j < 4; j++){
    int jj = tid + j*256;
    const float* c = coords + ((long long)i*NTOK + jj)*6;
    float d = c[0]*pe[0] + c[1]*pe[1] + c[2]*pe[2] + c[3]*pe[3] + c[4]*pe[4] + c[5]*pe[5];
    v[j] = -pt * d;
    mx = fmaxf(mx, v[j]);
  }
  mx = blockMax(mx, red);
  float s = 0.f;
  #pragma unroll
  for (int j = 0; j < 4; j++){ v[j] = __expf(v[j] - mx); s += v[j]; }
  s = blockSum(s, red);
  float inv = 1.f / s;
  #pragma unroll
  for (int j = 0; j < 4; j++) pos[(long long)i*NTOK + tid + j*256] = v[j] * inv;
}

// ------- per-row: softmax(S) -> attn -> entropy -> select -> attnc bf16, heat ----
__global__ __launch_bounds__(256) void rowproc_kernel(
    const float* __restrict__ S,        // (B,2,N,N) fp32 logits
    const float* __restrict__ pos,      // (N,N)
    __hip_bfloat16* __restrict__ attnc, // (B,N,N) bf16 out
    float* __restrict__ heat,           // (B,N)
    const float* __restrict__ gating, const float* __restrict__ h_temp)
{
  int row = blockIdx.x;           // b*N + i
  int b = row >> 10, i = row & 1023;
  int tid = threadIdx.x;
  __shared__ float a0[NTOK];
  __shared__ float a1[NTOK];
  __shared__ float red[4];
  float g = 1.f / (1.f + __expf(-gating[0]));
  float ht = h_temp[0];
  float ent[2];
  #pragma unroll
  for (int k = 0; k < 2; k++){
    const float* Sr = S + ((long long)((b*2 + k)*NTOK) + i) * NTOK;
    float v[4]; float mx = -INFINITY;
    #pragma unroll
    for (int j = 0; j < 4; j++){ v[j] = Sr[tid + j*256]; mx = fmaxf(mx, v[j]); }
    mx = blockMax(mx, red);
    float s = 0.f;
    #pragma unroll
    for (int j = 0; j < 4; j++){ v[j] = __expf(v[j] - mx); s += v[j]; }
    s = blockSum(s, red);
    float inv = 1.f / s;
    float e = 0.f;
    float* arow = k ? a1 : a0;
    #pragma unroll
    for (int j = 0; j < 4; j++){
      float p = v[j] * inv;
      float at = (1.f - g) * p + g * pos[(long long)i*NTOK + tid + j*256];
      arow[tid + j*256] = at;
      e += -at * __logf(at + 1e-8f);
    }
    ent[k] = blockSum(e, red);
  }
  float h0 = 2.f - 2.f / (1.f + __expf(-ht * ent[0]));
  float h1 = 2.f - 2.f / (1.f + __expf(-ht * ent[1]));
  bool fg = (h0 >= h1);
  if (tid == 0) heat[row] = fg ? h0 : h1;
  const float* sel = fg ? a0 : a1;
  __hip_bfloat16* outp = attnc + ((long long)b*NTOK + i) * NTOK;
  #pragma unroll
  for (int j = 0; j < 4; j++) outp[tid + j*256] = __float2bfloat16(sel[tid + j*256]);
}

// ---------------- convert kernels ----------------
// x (B,1025,768) fp32 -> xy bf16 (B,1025,1536) cols 0..767
__global__ __launch_bounds__(256) void conv_x_kernel(
    const float* __restrict__ x, __hip_bfloat16* __restrict__ xy)
{
  long long idx = (long long)blockIdx.x*256 + threadIdx.x;   // < B*1025*768
  int d = (int)(idx % DIM);
  long long br = idx / DIM;     // b*1025 + r
  xy[br*1536 + d] = __float2bfloat16(x[idx]);
}
// y CLS row -> xy row 0 cols 768..1535
__global__ __launch_bounds__(256) void conv_ycls_kernel(
    const float* __restrict__ y, __hip_bfloat16* __restrict__ xy)
{
  int idx = blockIdx.x*256 + threadIdx.x;    // < B*768
  int b = idx / DIM, d = idx % DIM;
  xy[(long long)b*NP1*1536 + DIM + d] = __float2bfloat16(y[(long long)b*NP1*DIM + d]);
}
// t fp32 -> ts1 = bf16(t*|S1|), ts2 = bf16(t*|S2|)
__global__ __launch_bounds__(256) void conv_ts_kernel(
    const float* __restrict__ t, const float* __restrict__ S1, const float* __restrict__ S2,
    __hip_bfloat16* __restrict__ ts1, __hip_bfloat16* __restrict__ ts2)
{
  long long idx = (long long)blockIdx.x*256 + threadIdx.x;   // < B*1024*768
  int d = (int)(idx % DIM);
  float v = t[idx];
  ts1[idx] = __float2bfloat16(v * fabsf(S1[d]));
  ts2[idx] = __float2bfloat16(v * fabsf(S2[d]));
}
// in fp32 [R][C] (row stride ldin, batch stride sIn) ->
//   outT bf16 [C][R] (batch stride sT), optional outS bf16 [R][C] (batch stride sS)
__global__ __launch_bounds__(256) void transpose_conv_kernel(
    const float* __restrict__ in, long long sIn, int ldin,
    __hip_bfloat16* __restrict__ outT, long long sT,
    __hip_bfloat16* __restrict__ outS, long long sS,
    int R, int C)
{
  __shared__ float tile[32][33];
  int bx = blockIdx.x, by = blockIdx.y, z = blockIdx.z;
  const float* inb = in + (long long)z*sIn;
  int tx = threadIdx.x & 31, ty = threadIdx.x >> 5;
  #pragma unroll
  for (int p = 0; p < 4; p++){
    int r = by*32 + p*8 + ty;
    int c = bx*32 + tx;
    float v = inb[(long long)r*ldin + c];
    tile[p*8 + ty][tx] = v;
    if (outS) outS[(long long)z*sS + (long long)r*C + c] = __float2bfloat16(v);
  }
  __syncthreads();
  #pragma unroll
  for (int p = 0; p < 4; p++){
    int c = bx*32 + p*8 + ty;
    int r = by*32 + tx;
    outT[(long long)z*sT + (long long)c*R + r] = __float2bfloat16(tile[tx][p*8 + ty]);
  }
}

// ---------------- bf16 MFMA GEMM, BT form: C[z][M][N] = A[z][M][K] * B[z>>shiftB][N][K]^T ----
// EPI: 0 = fp32 alpha*acc ; 1 = bf16 acc ; 2 = bf16 gelu(acc+bias) ; 3 = fp32 xres + heat*(acc+bias)
__device__ __forceinline__ void async16(const __bf16* gp, __bf16* lp){
  __builtin_amdgcn_global_load_lds(
      (const __attribute__((address_space(1))) void*)gp,
      (__attribute__((address_space(3))) void*)lp, 16, 0, 0);
}

template<int EPI>
__global__ __launch_bounds__(256) void mfma_gemm(
    const __bf16* __restrict__ A, const __bf16* __restrict__ Bm, void* __restrict__ Cv,
    int M, int N, int K, int lda, int ldb, int ldc,
    long long sAz, long long sBz, long long sCz,
    int shiftB, float alpha,
    const float* __restrict__ bias,
    const float* __restrict__ xres, long long sXz,
    const float* __restrict__ heat)
{
  __shared__ __align__(16) __bf16 Atile[128*32];
  __shared__ __align__(16) __bf16 Btile[128*32];

  const int tid  = threadIdx.x;
  const int lane = tid & 63;
  const int wv   = tid >> 6;
  const int wr   = wv >> 1, wc = wv & 1;
  const int n0 = blockIdx.x * 128, m0 = blockIdx.y * 128;
  const int z  = blockIdx.z;

  const __bf16* Ab = A  + (long long)z * sAz;
  const __bf16* Bb = Bm + (long long)(z >> shiftB) * sBz;

  const int fr_row = lane & 15;
  const int fr_k   = (lane >> 4) * 8;

  f32x4 acc[4][4] = {};

  for (int k0 = 0; k0 < K; k0 += 32){
    __syncthreads();
    #pragma unroll
    for (int i = 0; i < 2; i++){
      int s   = wv*128 + i*64 + lane;
      int row = s >> 2;
      int kc  = (s & 3) * 8;
      int gm = m0 + row; if (gm > M-1) gm = M-1;
      int gn = n0 + row; if (gn > N-1) gn = N-1;
      async16(Ab + (long long)gm*lda + (k0 + kc), &Atile[(wv*128 + i*64)*8]);
      async16(Bb + (long long)gn*ldb + (k0 + kc), &Btile[(wv*128 + i*64)*8]);
    }
    __syncthreads();
    bf16x8 af[4], bfv[4];
    #pragma unroll
    for (int r = 0; r < 4; r++)
      af[r] = *(const bf16x8*)&Atile[(wr*64 + r*16 + fr_row)*32 + fr_k];
    #pragma unroll
    for (int c = 0; c < 4; c++)
      bfv[c] = *(const bf16x8*)&Btile[(wc*64 + c*16 + fr_row)*32 + fr_k];
    #pragma unroll
    for (int r = 0; r < 4; r++)
      #pragma unroll
      for (int c = 0; c < 4; c++)
        acc[r][c] = __builtin_amdgcn_mfma_f32_16x16x32_bf16(af[r], bfv[c], acc[r][c], 0, 0, 0);
  }

  const int col_l = lane & 15;
  const int row_l = (lane >> 4) * 4;
  #pragma unroll
  for (int r = 0; r < 4; r++){
    #pragma unroll
    for (int c = 0; c < 4; c++){
      int gn  = n0 + wc*64 + c*16 + col_l;
      int gm0 = m0 + wr*64 + r*16 + row_l;
      if (gn >= N) continue;
      f32x4 v = acc[r][c];
      #pragma unroll
      for (int reg = 0; reg < 4; reg++){
        int gm = gm0 + reg;
        if (gm >= M) continue;
        float cval = v[reg];
        long long cidx = (long long)z*sCz + (long long)gm*ldc + gn;
        if (EPI == 0){
          ((float*)Cv)[cidx] = alpha * cval;
        } else if (EPI == 1){
          ((__hip_bfloat16*)Cv)[cidx] = __float2bfloat16(cval);
        } else if (EPI == 2){
          float h = cval + bias[gn];
          float ge = 0.5f * h * (1.f + erff(h * 0.70710678118654752f));
          ((__hip_bfloat16*)Cv)[cidx] = __float2bfloat16(ge);
        } else {
          float h = cval + bias[gn];
          float f = (gm == 0) ? 1.f : heat[(long long)z*NTOK + (gm - 1)];
          ((float*)Cv)[cidx] = xres[(long long)z*sXz + (long long)gm*ldc + gn] + f * h;
        }
      }
    }
  }
}

extern "C" void kernel_launch(void* const* d_in, const int* in_sizes, int n_in,
                              void* d_out, int out_size, void* d_ws, size_t ws_size,
                              hipStream_t stream)
{
  const float* x       = (const float*)d_in[0];
  const float* y       = (const float*)d_in[1];
  const float* coords  = (const float*)d_in[2];
  const float* U       = (const float*)d_in[3];
  const float* S1      = (const float*)d_in[4];
  const float* S2      = (const float*)d_in[5];
  const float* gating  = (const float*)d_in[6];
  const float* h_temp  = (const float*)d_in[7];
  const float* p_temp  = (const float*)d_in[8];
  const float* pos_emb = (const float*)d_in[9];
  const float* W1      = (const float*)d_in[10];
  const float* b1      = (const float*)d_in[11];
  const float* W2      = (const float*)d_in[12];
  const float* b2      = (const float*)d_in[13];
  float* out = (float*)d_out;
  char* ws = (char*)d_ws;

  // ---- workspace layout (bytes, 256-aligned), with lifetime overlays ----
  size_t off = 0;
  auto alloc = [&](size_t bytes){ size_t r = off; off = (off + bytes + 255) & ~(size_t)255; return r; };
  const long long NN  = (long long)NTOK * NTOK;
  const size_t o_pos  = alloc(NN * 4);                       // pos fp32, whole run
  const size_t o_t    = alloc((size_t)BB*NTOK*DIM * 4);      // t fp32; attnc bf16 overlays later
  const size_t o_S    = alloc((size_t)BB*2*NN * 4);          // S fp32; ts1/ts2 overlay before; hg overlays after
  const size_t o_xy   = alloc((size_t)BB*NP1*1536 * 2);      // xy bf16
  const size_t o_yb   = alloc((size_t)BB*NTOK*DIM * 2);      // yb bf16
  const size_t o_ybT  = alloc((size_t)BB*DIM*NTOK * 2);      // ybT bf16
  const size_t o_xs   = alloc((size_t)BB*2*NTOK*DIM * 2);    // xs bf16
  const size_t o_U    = alloc((size_t)DIM*DIM * 2);
  const size_t o_UT   = alloc((size_t)DIM*DIM * 2);
  const size_t o_W1T  = alloc((size_t)DFF*2*DIM * 2);
  const size_t o_W2T  = alloc((size_t)DIM*DFF * 2);
  const size_t o_heat = alloc((size_t)BB*NTOK * 4);

  float*  t_f    = (float*)(ws + o_t);
  float*  S_f    = (float*)(ws + o_S);
  __hip_bfloat16* ts1  = (__hip_bfloat16*)(ws + o_S);                               // overlay (pre-S)
  __hip_bfloat16* ts2  = (__hip_bfloat16*)(ws + o_S + (size_t)BB*NTOK*DIM*2);
  __hip_bfloat16* hg   = (__hip_bfloat16*)(ws + o_S);                               // overlay (post-S)
  __hip_bfloat16* attnc= (__hip_bfloat16*)(ws + o_t);                               // overlay (post-t)
  __hip_bfloat16* xy   = (__hip_bfloat16*)(ws + o_xy);
  __hip_bfloat16* yb   = (__hip_bfloat16*)(ws + o_yb);
  __hip_bfloat16* ybT  = (__hip_bfloat16*)(ws + o_ybT);
  __hip_bfloat16* xs   = (__hip_bfloat16*)(ws + o_xs);
  __hip_bfloat16* Ubf  = (__hip_bfloat16*)(ws + o_U);
  __hip_bfloat16* UT   = (__hip_bfloat16*)(ws + o_UT);
  __hip_bfloat16* W1T  = (__hip_bfloat16*)(ws + o_W1T);
  __hip_bfloat16* W2T  = (__hip_bfloat16*)(ws + o_W2T);
  float* pos  = (float*)(ws + o_pos);
  float* heat = (float*)(ws + o_heat);

  const float scale = 0.03608439182435161f; // 768^-0.5
  dim3 blk(256);

  // 1) pos softmax + input conversions
  pos_kernel<<<dim3(NTOK), blk, 0, stream>>>(coords, pos_emb, p_temp, pos);
  conv_x_kernel<<<dim3((BB*NP1*DIM)/256), blk, 0, stream>>>(x, xy);
  conv_ycls_kernel<<<dim3((BB*DIM)/256), blk, 0, stream>>>(y, xy);
  transpose_conv_kernel<<<dim3(DIM/32, DIM/32, 1), blk, 0, stream>>>(
      U, 0LL, DIM, UT, 0LL, Ubf, 0LL, DIM, DIM);
  transpose_conv_kernel<<<dim3(DFF/32, (2*DIM)/32, 1), blk, 0, stream>>>(
      W1, 0LL, DFF, W1T, 0LL, nullptr, 0LL, 2*DIM, DFF);
  transpose_conv_kernel<<<dim3(DIM/32, DFF/32, 1), blk, 0, stream>>>(
      W2, 0LL, DIM, W2T, 0LL, nullptr, 0LL, DFF, DIM);
  transpose_conv_kernel<<<dim3(DIM/32, NTOK/32, BB), blk, 0, stream>>>(
      y + DIM, (long long)NP1*DIM, DIM, ybT, (long long)DIM*NTOK, yb, (long long)NTOK*DIM, NTOK, DIM);

  // 2) t = xb @ U^T  (A = xy rows 1.., cols 0..767)
  mfma_gemm<0><<<dim3(DIM/128, NTOK/128, BB), blk, 0, stream>>>(
      (const __bf16*)(xy + 1536), (const __bf16*)Ubf, t_f,
      NTOK, DIM, DIM, 1536, DIM, DIM,
      (long long)NP1*1536, 0LL, (long long)NTOK*DIM,
      0, 1.f, nullptr, nullptr, 0LL, nullptr);

  // 2b) ts1/ts2 = bf16(t * |S1,2|)
  conv_ts_kernel<<<dim3((BB*NTOK*DIM)/256), blk, 0, stream>>>(t_f, S1, S2, ts1, ts2);

  // 3) xs_k = ts_k @ U
  mfma_gemm<1><<<dim3(DIM/128, NTOK/128, BB), blk, 0, stream>>>(
      (const __bf16*)ts1, (const __bf16*)UT, xs,
      NTOK, DIM, DIM, DIM, DIM, DIM,
      (long long)NTOK*DIM, 0LL, 2LL*NTOK*DIM,
      0, 1.f, nullptr, nullptr, 0LL, nullptr);
  mfma_gemm<1><<<dim3(DIM/128, NTOK/128, BB), blk, 0, stream>>>(
      (const __bf16*)ts2, (const __bf16*)UT, xs + (long long)NTOK*DIM,
      NTOK, DIM, DIM, DIM, DIM, DIM,
      (long long)NTOK*DIM, 0LL, 2LL*NTOK*DIM,
      0, 1.f, nullptr, nullptr, 0LL, nullptr);

  // 4) S[z] = scale * xs[z] @ yb[z>>1]^T
  mfma_gemm<0><<<dim3(NTOK/128, NTOK/128, 2*BB), blk, 0, stream>>>(
      (const __bf16*)xs, (const __bf16*)yb, S_f,
      NTOK, NTOK, DIM, DIM, DIM, NTOK,
      (long long)NTOK*DIM, (long long)NTOK*DIM, NN,
      1, scale, nullptr, nullptr, 0LL, nullptr);

  // 5) softmax + mix + entropy + select
  rowproc_kernel<<<dim3(BB*NTOK), blk, 0, stream>>>(S_f, pos, attnc, heat, gating, h_temp);

  // 6) y_out = attnc @ yb  -> xy rows 1.., cols 768..1535 (bf16, ldc=1536)
  mfma_gemm<1><<<dim3(DIM/128, NTOK/128, BB), blk, 0, stream>>>(
      (const __bf16*)attnc, (const __bf16*)ybT, xy + 1536 + DIM,
      NTOK, DIM, NTOK, NTOK, NTOK, 1536,
      NN, (long long)DIM*NTOK, (long long)NP1*1536,
      0, 1.f, nullptr, nullptr, 0LL, nullptr);

  // 7) hg = gelu(xy @ W1^T + b1)  (M=1025, N=3072, K=1536)
  mfma_gemm<2><<<dim3(DFF/128, (NP1+127)/128, BB), blk, 0, stream>>>(
      (const __bf16*)xy, (const __bf16*)W1T, hg,
      NP1, DFF, 2*DIM, 1536, 1536, DFF,
      (long long)NP1*1536, 0LL, (long long)NP1*DFF,
      0, 1.f, b1, nullptr, 0LL, nullptr);

  // 8) out = x + heatrow * (hg @ W2^T + b2)  (M=1025, N=768, K=3072)
  mfma_gemm<3><<<dim3(DIM/128, (NP1+127)/128, BB), blk, 0, stream>>>(
      (const __bf16*)hg, (const __bf16*)W2T, out,
      NP1, DIM, DFF, DFF, DFF, DIM,
      (long long)NP1*DFF, 0LL, (long long)NP1*DIM,
      0, 1.f, b2, x, (long long)NP1*DIM, heat);
}

// Round 3
// 619.235 us; speedup vs baseline: 6.9366x; 1.0772x over previous
//
#include <hip/hip_runtime.h>
#include <hip/hip_bf16.h>
#include <math.h>

#define BB   8
#define NTOK 1024
#define DIM  768
#define DFF  3072
#define NP1  1025

typedef __bf16 bf16x8 __attribute__((ext_vector_type(8)));
typedef float  f32x4  __attribute__((ext_vector_type(4)));

// ---------------- reductions (wave = 64) ----------------
__device__ __forceinline__ float waveMax(float v){
  #pragma unroll
  for (int o = 32; o > 0; o >>= 1) v = fmaxf(v, __shfl_down(v, o, 64));
  return v;
}
__device__ __forceinline__ float waveSum(float v){
  #pragma unroll
  for (int o = 32; o > 0; o >>= 1) v += __shfl_down(v, o, 64);
  return v;
}
__device__ __forceinline__ float blockMax(float v, float* red){
  int lane = threadIdx.x & 63, w = threadIdx.x >> 6;
  v = waveMax(v);
  if (lane == 0) red[w] = v;
  __syncthreads();
  float r = fmaxf(fmaxf(red[0], red[1]), fmaxf(red[2], red[3]));
  __syncthreads();
  return r;
}
__device__ __forceinline__ float blockSum(float v, float* red){
  int lane = threadIdx.x & 63, w = threadIdx.x >> 6;
  v = waveSum(v);
  if (lane == 0) red[w] = v;
  __syncthreads();
  float r = red[0] + red[1] + red[2] + red[3];
  __syncthreads();
  return r;
}

// ---------------- pos softmax ----------------
__global__ __launch_bounds__(256) void pos_kernel(
    const float* __restrict__ coords, const float* __restrict__ pos_emb,
    const float* __restrict__ p_temp, float* __restrict__ pos)
{
  int i = blockIdx.x;
  int tid = threadIdx.x;
  __shared__ float red[4];
  __shared__ float pe[6];
  if (tid < 6) pe[tid] = pos_emb[i*6 + tid];
  __syncthreads();
  float pt = fabsf(p_temp[0]);
  float v[4]; float mx = -INFINITY;
  #pragma unroll
  for (int j = 0; j < 4; j++){
    int jj = tid + j*256;
    const float* c = coords + ((long long)i*NTOK + jj)*6;
    float d = c[0]*pe[0] + c[1]*pe[1] + c[2]*pe[2] + c[3]*pe[3] + c[4]*pe[4] + c[5]*pe[5];
    v[j] = -pt * d;
    mx = fmaxf(mx, v[j]);
  }
  mx = blockMax(mx, red);
  float s = 0.f;
  #pragma unroll
  for (int j = 0; j < 4; j++){ v[j] = __expf(v[j] - mx); s += v[j]; }
  s = blockSum(s, red);
  float inv = 1.f / s;
  #pragma unroll
  for (int j = 0; j < 4; j++) pos[(long long)i*NTOK + tid + j*256] = v[j] * inv;
}

// ------- per-row: softmax(S) -> attn -> entropy -> select -> attnc bf16, heat ----
// S layout: (k, b, i, j) = ((k*8+b)*N + i)*N + j, fp32
__global__ __launch_bounds__(256) void rowproc_kernel(
    const float* __restrict__ S,
    const float* __restrict__ pos,
    __hip_bfloat16* __restrict__ attnc, // (B,N,N)
    float* __restrict__ heat,           // (B,N)
    const float* __restrict__ gating, const float* __restrict__ h_temp)
{
  int row = blockIdx.x;           // b*N + i
  int b = row >> 10, i = row & 1023;
  int tid = threadIdx.x;
  __shared__ __align__(16) float a0[NTOK];
  __shared__ __align__(16) float a1[NTOK];
  __shared__ float red[4];
  float g = 1.f / (1.f + __expf(-gating[0]));
  float ht = h_temp[0];
  float ent[2];
  const int c0 = tid * 4;
  f32x4 pv = *(const f32x4*)&pos[(long long)i*NTOK + c0];
  #pragma unroll
  for (int k = 0; k < 2; k++){
    const float* Sr = S + ((long long)((k*8 + b)*NTOK) + i) * NTOK;
    f32x4 v = *(const f32x4*)&Sr[c0];
    float mx = fmaxf(fmaxf(v[0], v[1]), fmaxf(v[2], v[3]));
    mx = blockMax(mx, red);
    float s = 0.f;
    #pragma unroll
    for (int j = 0; j < 4; j++){ v[j] = __expf(v[j] - mx); s += v[j]; }
    s = blockSum(s, red);
    float inv = 1.f / s;
    float e = 0.f;
    float* arow = k ? a1 : a0;
    f32x4 at;
    #pragma unroll
    for (int j = 0; j < 4; j++){
      at[j] = (1.f - g) * (v[j] * inv) + g * pv[j];
      e += -at[j] * __logf(at[j] + 1e-8f);
    }
    *(f32x4*)&arow[c0] = at;
    ent[k] = blockSum(e, red);
  }
  float h0 = 2.f - 2.f / (1.f + __expf(-ht * ent[0]));
  float h1 = 2.f - 2.f / (1.f + __expf(-ht * ent[1]));
  bool fg = (h0 >= h1);
  if (tid == 0) heat[row] = fg ? h0 : h1;
  const float* sel = fg ? a0 : a1;
  f32x4 sv = *(const f32x4*)&sel[c0];
  union { __hip_bfloat16 h[4]; uint2 u; } pk;
  #pragma unroll
  for (int j = 0; j < 4; j++) pk.h[j] = __float2bfloat16(sv[j]);
  *(uint2*)(attnc + ((long long)b*NTOK + i)*NTOK + c0) = pk.u;
}

// ---------------- x,y -> xy bf16 (B,1025,1536) ----------------
__global__ __launch_bounds__(256) void conv_xy_kernel(
    const float* __restrict__ x, const float* __restrict__ y, __hip_bfloat16* __restrict__ xy)
{
  long long idx = (long long)blockIdx.x*256 + threadIdx.x;   // < B*1025*768
  int d = (int)(idx % DIM);
  long long br = idx / DIM;     // b*1025 + r
  int r = (int)(br % NP1);
  xy[br*1536 + d] = __float2bfloat16(x[idx]);
  if (r == 0) xy[br*1536 + DIM + d] = __float2bfloat16(y[idx]);
}

// in fp32 [R][C] -> outT bf16 [C][R]; optional straight outS bf16 [R][C];
// optional scaled transposes outT1/outT2 (scaled by |sc1[r]|, |sc2[r]| along original row r)
__global__ __launch_bounds__(256) void transpose_conv_kernel(
    const float* __restrict__ in, long long sIn, int ldin,
    __hip_bfloat16* __restrict__ outT, long long sT,
    __hip_bfloat16* __restrict__ outS, long long sS,
    int R, int C,
    const float* __restrict__ sc1, const float* __restrict__ sc2,
    __hip_bfloat16* __restrict__ outT1, __hip_bfloat16* __restrict__ outT2)
{
  __shared__ float tile[32][33];
  int bx = blockIdx.x, by = blockIdx.y, z = blockIdx.z;
  const float* inb = in + (long long)z*sIn;
  int tx = threadIdx.x & 31, ty = threadIdx.x >> 5;
  #pragma unroll
  for (int p = 0; p < 4; p++){
    int r = by*32 + p*8 + ty;
    int c = bx*32 + tx;
    float v = inb[(long long)r*ldin + c];
    tile[p*8 + ty][tx] = v;
    if (outS) outS[(long long)z*sS + (long long)r*C + c] = __float2bfloat16(v);
  }
  __syncthreads();
  #pragma unroll
  for (int p = 0; p < 4; p++){
    int c = bx*32 + p*8 + ty;   // original col
    int r = by*32 + tx;         // original row
    float v = tile[tx][p*8 + ty];
    long long oidx = (long long)z*sT + (long long)c*R + r;
    outT[oidx] = __float2bfloat16(v);
    if (outT1) outT1[(long long)c*R + r] = __float2bfloat16(v * fabsf(sc1[r]));
    if (outT2) outT2[(long long)c*R + r] = __float2bfloat16(v * fabsf(sc2[r]));
  }
}

// ---------------- bf16 MFMA GEMM, BT form ----------------
// C[z][M][N] = A[(z&maskA)][M][K] * B[(z>>shiftB)&maskB][N][K]^T
// EPI: 0 = fp32 alpha*acc ; 1 = bf16 acc ; 2 = bf16 gelu(acc+bias) ;
//      3 = fp32 xres + heatrow*(acc+bias), rows flattened (B*1025)
__device__ __forceinline__ void async16(const __bf16* gp, __bf16* lp){
  __builtin_amdgcn_global_load_lds(
      (const __attribute__((address_space(1))) void*)gp,
      (__attribute__((address_space(3))) void*)lp, 16, 0, 0);
}

template<int EPI>
__global__ __launch_bounds__(256) void mfma_gemm(
    const __bf16* __restrict__ A, const __bf16* __restrict__ Bm, void* __restrict__ Cv,
    int M, int N, int K, int lda, int ldb, int ldc,
    long long sAz, long long sBz, long long sCz,
    int maskA, int shiftB, int maskB, float alpha,
    const float* __restrict__ bias,
    const float* __restrict__ xres,
    const float* __restrict__ heat)
{
  __shared__ __align__(16) __bf16 Atile[128*32];
  __shared__ __align__(16) __bf16 Btile[128*32];

  const int tid  = threadIdx.x;
  const int lane = tid & 63;
  const int wv   = tid >> 6;
  const int wr   = wv >> 1, wc = wv & 1;
  const int n0 = blockIdx.x * 128, m0 = blockIdx.y * 128;
  const int z  = blockIdx.z;

  const __bf16* Ab = A  + (long long)(z & maskA) * sAz;
  const __bf16* Bb = Bm + (long long)((z >> shiftB) & maskB) * sBz;

  const int fr_row = lane & 15;
  const int fr_k   = (lane >> 4) * 8;

  f32x4 acc[4][4] = {};

  for (int k0 = 0; k0 < K; k0 += 32){
    __syncthreads();
    #pragma unroll
    for (int i = 0; i < 2; i++){
      int s   = wv*128 + i*64 + lane;
      int row = s >> 2;
      int kc  = (s & 3) * 8;
      int gm = m0 + row; if (gm > M-1) gm = M-1;
      int gn = n0 + row; if (gn > N-1) gn = N-1;
      async16(Ab + (long long)gm*lda + (k0 + kc), &Atile[(wv*128 + i*64)*8]);
      async16(Bb + (long long)gn*ldb + (k0 + kc), &Btile[(wv*128 + i*64)*8]);
    }
    __syncthreads();
    bf16x8 af[4], bfv[4];
    #pragma unroll
    for (int r = 0; r < 4; r++)
      af[r] = *(const bf16x8*)&Atile[(wr*64 + r*16 + fr_row)*32 + fr_k];
    #pragma unroll
    for (int c = 0; c < 4; c++)
      bfv[c] = *(const bf16x8*)&Btile[(wc*64 + c*16 + fr_row)*32 + fr_k];
    #pragma unroll
    for (int r = 0; r < 4; r++)
      #pragma unroll
      for (int c = 0; c < 4; c++)
        acc[r][c] = __builtin_amdgcn_mfma_f32_16x16x32_bf16(af[r], bfv[c], acc[r][c], 0, 0, 0);
  }

  const int col_l = lane & 15;
  const int row_l = (lane >> 4) * 4;
  #pragma unroll
  for (int r = 0; r < 4; r++){
    #pragma unroll
    for (int c = 0; c < 4; c++){
      int gn  = n0 + wc*64 + c*16 + col_l;
      int gm0 = m0 + wr*64 + r*16 + row_l;
      if (gn >= N) continue;
      f32x4 v = acc[r][c];
      #pragma unroll
      for (int reg = 0; reg < 4; reg++){
        int gm = gm0 + reg;
        if (gm >= M) continue;
        float cval = v[reg];
        long long cidx = (long long)z*sCz + (long long)gm*ldc + gn;
        if (EPI == 0){
          ((float*)Cv)[cidx] = alpha * cval;
        } else if (EPI == 1){
          ((__hip_bfloat16*)Cv)[cidx] = __float2bfloat16(cval);
        } else if (EPI == 2){
          float h = cval + bias[gn];
          float ge = 0.5f * h * (1.f + erff(h * 0.70710678118654752f));
          ((__hip_bfloat16*)Cv)[cidx] = __float2bfloat16(ge);
        } else {
          float h = cval + bias[gn];
          int bq = gm / NP1;             // constant division -> magic mul
          int rr = gm - bq * NP1;
          float f = (rr == 0) ? 1.f : heat[bq*NTOK + (rr - 1)];
          ((float*)Cv)[cidx] = xres[cidx] + f * h;
        }
      }
    }
  }
}

extern "C" void kernel_launch(void* const* d_in, const int* in_sizes, int n_in,
                              void* d_out, int out_size, void* d_ws, size_t ws_size,
                              hipStream_t stream)
{
  const float* x       = (const float*)d_in[0];
  const float* y       = (const float*)d_in[1];
  const float* coords  = (const float*)d_in[2];
  const float* U       = (const float*)d_in[3];
  const float* S1      = (const float*)d_in[4];
  const float* S2      = (const float*)d_in[5];
  const float* gating  = (const float*)d_in[6];
  const float* h_temp  = (const float*)d_in[7];
  const float* p_temp  = (const float*)d_in[8];
  const float* pos_emb = (const float*)d_in[9];
  const float* W1      = (const float*)d_in[10];
  const float* b1      = (const float*)d_in[11];
  const float* W2      = (const float*)d_in[12];
  const float* b2      = (const float*)d_in[13];
  float* out = (float*)d_out;
  char* ws = (char*)d_ws;

  size_t off = 0;
  auto alloc = [&](size_t bytes){ size_t r = off; off = (off + bytes + 255) & ~(size_t)255; return r; };
  const long long NN  = (long long)NTOK * NTOK;
  const long long DD  = (long long)DIM * DIM;
  const size_t o_pos  = alloc(NN * 4);                       // pos fp32
  const size_t o_S    = alloc((size_t)2*BB*NN * 4);          // S fp32 (k,b,N,N); hg bf16 overlays after rowproc
  const size_t o_xy   = alloc((size_t)BB*NP1*1536 * 2);      // xy bf16
  const size_t o_yb   = alloc((size_t)BB*NTOK*DIM * 2);      // yb bf16
  const size_t o_ybT  = alloc((size_t)BB*DIM*NTOK * 2);      // ybT bf16
  const size_t o_xs   = alloc((size_t)2*BB*NTOK*DIM * 2);    // xs bf16 (k,b,N,D)
  const size_t o_attn = alloc((size_t)BB*NN * 2);            // attnc bf16
  const size_t o_UT   = alloc((size_t)DD * 2);
  const size_t o_UTs  = alloc((size_t)2*DD * 2);             // UTs1,UTs2
  const size_t o_Mk   = alloc((size_t)2*DD * 2);             // M1,M2 bf16
  const size_t o_W1T  = alloc((size_t)DFF*2*DIM * 2);
  const size_t o_W2T  = alloc((size_t)DIM*DFF * 2);
  const size_t o_heat = alloc((size_t)BB*NTOK * 4);

  float*  S_f  = (float*)(ws + o_S);
  __hip_bfloat16* hg   = (__hip_bfloat16*)(ws + o_S);        // overlay (post-rowproc)
  __hip_bfloat16* xy   = (__hip_bfloat16*)(ws + o_xy);
  __hip_bfloat16* yb   = (__hip_bfloat16*)(ws + o_yb);
  __hip_bfloat16* ybT  = (__hip_bfloat16*)(ws + o_ybT);
  __hip_bfloat16* xs   = (__hip_bfloat16*)(ws + o_xs);
  __hip_bfloat16* attnc= (__hip_bfloat16*)(ws + o_attn);
  __hip_bfloat16* UT   = (__hip_bfloat16*)(ws + o_UT);
  __hip_bfloat16* UTs  = (__hip_bfloat16*)(ws + o_UTs);
  __hip_bfloat16* Mk   = (__hip_bfloat16*)(ws + o_Mk);
  __hip_bfloat16* W1T  = (__hip_bfloat16*)(ws + o_W1T);
  __hip_bfloat16* W2T  = (__hip_bfloat16*)(ws + o_W2T);
  float* pos  = (float*)(ws + o_pos);
  float* heat = (float*)(ws + o_heat);

  const float scale = 0.03608439182435161f; // 768^-0.5
  dim3 blk(256);

  // ---- prep ----
  pos_kernel<<<dim3(NTOK), blk, 0, stream>>>(coords, pos_emb, p_temp, pos);
  conv_xy_kernel<<<dim3((BB*NP1*DIM)/256), blk, 0, stream>>>(x, y, xy);
  transpose_conv_kernel<<<dim3(DIM/32, DIM/32, 1), blk, 0, stream>>>(
      U, 0LL, DIM, UT, 0LL, nullptr, 0LL, DIM, DIM, S1, S2, UTs, UTs + DD);
  transpose_conv_kernel<<<dim3(DFF/32, (2*DIM)/32, 1), blk, 0, stream>>>(
      W1, 0LL, DFF, W1T, 0LL, nullptr, 0LL, 2*DIM, DFF, nullptr, nullptr, nullptr, nullptr);
  transpose_conv_kernel<<<dim3(DIM/32, DFF/32, 1), blk, 0, stream>>>(
      W2, 0LL, DIM, W2T, 0LL, nullptr, 0LL, DFF, DIM, nullptr, nullptr, nullptr, nullptr);
  transpose_conv_kernel<<<dim3(DIM/32, NTOK/32, BB), blk, 0, stream>>>(
      y + DIM, (long long)NP1*DIM, DIM, ybT, (long long)DIM*NTOK, yb, (long long)NTOK*DIM,
      NTOK, DIM, nullptr, nullptr, nullptr, nullptr);

  // ---- G1: M_k = UT @ UTs_k^T  (symmetric, so usable as B directly), z=2 ----
  mfma_gemm<1><<<dim3(DIM/128, DIM/128, 2), blk, 0, stream>>>(
      (const __bf16*)UT, (const __bf16*)UTs, Mk,
      DIM, DIM, DIM, DIM, DIM, DIM,
      0LL, DD, DD, 0, 0, 1, 1.f, nullptr, nullptr, nullptr);

  // ---- G2: xs[k,b] = xb[b] @ M_k^T, z=k*8+b ----
  mfma_gemm<1><<<dim3(DIM/128, NTOK/128, 16), blk, 0, stream>>>(
      (const __bf16*)(xy + 1536), (const __bf16*)Mk, xs,
      NTOK, DIM, DIM, 1536, DIM, DIM,
      (long long)NP1*1536, DD, (long long)NTOK*DIM,
      7, 3, 1, 1.f, nullptr, nullptr, nullptr);

  // ---- G3: S[k,b] = scale * xs[k,b] @ yb[b]^T ----
  mfma_gemm<0><<<dim3(NTOK/128, NTOK/128, 16), blk, 0, stream>>>(
      (const __bf16*)xs, (const __bf16*)yb, S_f,
      NTOK, NTOK, DIM, DIM, DIM, NTOK,
      (long long)NTOK*DIM, (long long)NTOK*DIM, NN,
      15, 0, 7, scale, nullptr, nullptr, nullptr);

  // ---- rowproc: softmax + mix + entropy + select ----
  rowproc_kernel<<<dim3(BB*NTOK), blk, 0, stream>>>(S_f, pos, attnc, heat, gating, h_temp);

  // ---- G4: y_out[b] = attnc[b] @ ybT[b]^T -> xy cols 768.., rows 1.. ----
  mfma_gemm<1><<<dim3(DIM/128, NTOK/128, BB), blk, 0, stream>>>(
      (const __bf16*)attnc, (const __bf16*)ybT, xy + 1536 + DIM,
      NTOK, DIM, NTOK, NTOK, NTOK, 1536,
      NN, (long long)DIM*NTOK, (long long)NP1*1536,
      7, 0, 7, 1.f, nullptr, nullptr, nullptr);

  // ---- G5: hg = gelu(xy @ W1T^T + b1), flattened M=8200 ----
  mfma_gemm<2><<<dim3(DFF/128, (BB*NP1 + 127)/128, 1), blk, 0, stream>>>(
      (const __bf16*)xy, (const __bf16*)W1T, hg,
      BB*NP1, DFF, 2*DIM, 1536, 1536, DFF,
      0LL, 0LL, 0LL, 0, 0, 0, 1.f, b1, nullptr, nullptr);

  // ---- G6: out = x + heatrow*(hg @ W2T^T + b2), flattened M=8200 ----
  mfma_gemm<3><<<dim3(DIM/128, (BB*NP1 + 127)/128, 1), blk, 0, stream>>>(
      (const __bf16*)hg, (const __bf16*)W2T, out,
      BB*NP1, DIM, DFF, DFF, DFF, DIM,
      0LL, 0LL, 0LL, 0, 0, 0, 1.f, b2, x, heat);
}

// Round 4
// 578.984 us; speedup vs baseline: 7.4188x; 1.0695x over previous
//
#include <hip/hip_runtime.h>
#include <hip/hip_bf16.h>
#include <math.h>

#define BB   8
#define NTOK 1024
#define DIM  768
#define DFF  3072
#define NP1  1025

typedef __bf16 bf16x8 __attribute__((ext_vector_type(8)));
typedef float  f32x4  __attribute__((ext_vector_type(4)));
typedef float  f32x16 __attribute__((ext_vector_type(16)));

// ---------------- reductions (wave = 64) ----------------
__device__ __forceinline__ float waveMax(float v){
  #pragma unroll
  for (int o = 32; o > 0; o >>= 1) v = fmaxf(v, __shfl_down(v, o, 64));
  return v;
}
__device__ __forceinline__ float waveSum(float v){
  #pragma unroll
  for (int o = 32; o > 0; o >>= 1) v += __shfl_down(v, o, 64);
  return v;
}
__device__ __forceinline__ float blockMax(float v, float* red){
  int lane = threadIdx.x & 63, w = threadIdx.x >> 6;
  v = waveMax(v);
  if (lane == 0) red[w] = v;
  __syncthreads();
  float r = fmaxf(fmaxf(red[0], red[1]), fmaxf(red[2], red[3]));
  __syncthreads();
  return r;
}
__device__ __forceinline__ float blockSum(float v, float* red){
  int lane = threadIdx.x & 63, w = threadIdx.x >> 6;
  v = waveSum(v);
  if (lane == 0) red[w] = v;
  __syncthreads();
  float r = red[0] + red[1] + red[2] + red[3];
  __syncthreads();
  return r;
}

// ---------------- pos softmax ----------------
__global__ __launch_bounds__(256) void pos_kernel(
    const float* __restrict__ coords, const float* __restrict__ pos_emb,
    const float* __restrict__ p_temp, float* __restrict__ pos)
{
  int i = blockIdx.x;
  int tid = threadIdx.x;
  __shared__ float red[4];
  __shared__ float pe[6];
  if (tid < 6) pe[tid] = pos_emb[i*6 + tid];
  __syncthreads();
  float pt = fabsf(p_temp[0]);
  float v[4]; float mx = -INFINITY;
  #pragma unroll
  for (int j = 0; j < 4; j++){
    int jj = tid + j*256;
    const float* c = coords + ((long long)i*NTOK + jj)*6;
    float d = c[0]*pe[0] + c[1]*pe[1] + c[2]*pe[2] + c[3]*pe[3] + c[4]*pe[4] + c[5]*pe[5];
    v[j] = -pt * d;
    mx = fmaxf(mx, v[j]);
  }
  mx = blockMax(mx, red);
  float s = 0.f;
  #pragma unroll
  for (int j = 0; j < 4; j++){ v[j] = __expf(v[j] - mx); s += v[j]; }
  s = blockSum(s, red);
  float inv = 1.f / s;
  #pragma unroll
  for (int j = 0; j < 4; j++) pos[(long long)i*NTOK + tid + j*256] = v[j] * inv;
}

// ------- per-row: softmax(S bf16) -> attn -> entropy -> select -> attnc bf16, heat ----
// S layout: (k, b, i, j) = ((k*8+b)*N + i)*N + j, bf16
__global__ __launch_bounds__(256) void rowproc_kernel(
    const __hip_bfloat16* __restrict__ S,
    const float* __restrict__ pos,
    __hip_bfloat16* __restrict__ attnc, // (B,N,N)
    float* __restrict__ heat,           // (B,N)
    const float* __restrict__ gating, const float* __restrict__ h_temp)
{
  int row = blockIdx.x;           // b*N + i
  int b = row >> 10, i = row & 1023;
  int tid = threadIdx.x;
  __shared__ __align__(16) float a0[NTOK];
  __shared__ __align__(16) float a1[NTOK];
  __shared__ float red[4];
  float g = 1.f / (1.f + __expf(-gating[0]));
  float ht = h_temp[0];
  float ent[2];
  const int c0 = tid * 4;
  f32x4 pv = *(const f32x4*)&pos[(long long)i*NTOK + c0];
  #pragma unroll
  for (int k = 0; k < 2; k++){
    const __hip_bfloat16* Sr = S + ((long long)((k*8 + b)*NTOK) + i) * NTOK;
    union { uint2 u; __hip_bfloat16 h[4]; } ld;
    ld.u = *(const uint2*)&Sr[c0];
    f32x4 v;
    #pragma unroll
    for (int j = 0; j < 4; j++) v[j] = __bfloat162float(ld.h[j]);
    float mx = fmaxf(fmaxf(v[0], v[1]), fmaxf(v[2], v[3]));
    mx = blockMax(mx, red);
    float s = 0.f;
    #pragma unroll
    for (int j = 0; j < 4; j++){ v[j] = __expf(v[j] - mx); s += v[j]; }
    s = blockSum(s, red);
    float inv = 1.f / s;
    float e = 0.f;
    float* arow = k ? a1 : a0;
    f32x4 at;
    #pragma unroll
    for (int j = 0; j < 4; j++){
      at[j] = (1.f - g) * (v[j] * inv) + g * pv[j];
      e += -at[j] * __logf(at[j] + 1e-8f);
    }
    *(f32x4*)&arow[c0] = at;
    ent[k] = blockSum(e, red);
  }
  float h0 = 2.f - 2.f / (1.f + __expf(-ht * ent[0]));
  float h1 = 2.f - 2.f / (1.f + __expf(-ht * ent[1]));
  bool fg = (h0 >= h1);
  if (tid == 0) heat[row] = fg ? h0 : h1;
  const float* sel = fg ? a0 : a1;
  f32x4 sv = *(const f32x4*)&sel[c0];
  union { __hip_bfloat16 h[4]; uint2 u; } pk;
  #pragma unroll
  for (int j = 0; j < 4; j++) pk.h[j] = __float2bfloat16(sv[j]);
  *(uint2*)(attnc + ((long long)b*NTOK + i)*NTOK + c0) = pk.u;
}

// ---------------- x,y -> xy bf16 (B,1025,1536) ----------------
__global__ __launch_bounds__(256) void conv_xy_kernel(
    const float* __restrict__ x, const float* __restrict__ y, __hip_bfloat16* __restrict__ xy)
{
  long long idx = (long long)blockIdx.x*256 + threadIdx.x;   // < B*1025*768
  int d = (int)(idx % DIM);
  long long br = idx / DIM;     // b*1025 + r
  int r = (int)(br % NP1);
  xy[br*1536 + d] = __float2bfloat16(x[idx]);
  if (r == 0) xy[br*1536 + DIM + d] = __float2bfloat16(y[idx]);
}

// in fp32 [R][C] -> outT bf16 [C][R]; optional straight outS bf16 [R][C];
// optional scaled transposes outT1/outT2 (|sc1[r]|,|sc2[r]| along original row r)
__global__ __launch_bounds__(256) void transpose_conv_kernel(
    const float* __restrict__ in, long long sIn, int ldin,
    __hip_bfloat16* __restrict__ outT, long long sT,
    __hip_bfloat16* __restrict__ outS, long long sS,
    int R, int C,
    const float* __restrict__ sc1, const float* __restrict__ sc2,
    __hip_bfloat16* __restrict__ outT1, __hip_bfloat16* __restrict__ outT2)
{
  __shared__ float tile[32][33];
  int bx = blockIdx.x, by = blockIdx.y, z = blockIdx.z;
  const float* inb = in + (long long)z*sIn;
  int tx = threadIdx.x & 31, ty = threadIdx.x >> 5;
  #pragma unroll
  for (int p = 0; p < 4; p++){
    int r = by*32 + p*8 + ty;
    int c = bx*32 + tx;
    float v = inb[(long long)r*ldin + c];
    tile[p*8 + ty][tx] = v;
    if (outS) outS[(long long)z*sS + (long long)r*C + c] = __float2bfloat16(v);
  }
  __syncthreads();
  #pragma unroll
  for (int p = 0; p < 4; p++){
    int c = bx*32 + p*8 + ty;   // original col
    int r = by*32 + tx;         // original row
    float v = tile[tx][p*8 + ty];
    long long oidx = (long long)z*sT + (long long)c*R + r;
    outT[oidx] = __float2bfloat16(v);
    if (outT1) outT1[(long long)c*R + r] = __float2bfloat16(v * fabsf(sc1[r]));
    if (outT2) outT2[(long long)c*R + r] = __float2bfloat16(v * fabsf(sc2[r]));
  }
}

// ---------------- bf16 MFMA GEMM (32x32x16), BT form ----------------
// C[z][M][N] = alpha * A[(z&maskA)][M][K] * B[(z>>shiftB)&maskB][N][K]^T  (+ epilogue)
// EPI: 1 = bf16 alpha*acc ; 2 = bf16 gelu(acc+bias) ; 3 = fp32 xres + heatrow*(acc+bias) flat rows
// LDS tiles are XOR-swizzled in 16B chunks: slot(row,kcs) holds global kc = kcs ^ ((row>>1)&3).
__device__ __forceinline__ void async16(const __bf16* gp, __bf16* lp){
  __builtin_amdgcn_global_load_lds(
      (const __attribute__((address_space(1))) void*)gp,
      (__attribute__((address_space(3))) void*)lp, 16, 0, 0);
}

template<int EPI>
__global__ __launch_bounds__(256) void mfma_gemm(
    const __bf16* __restrict__ A, const __bf16* __restrict__ Bm, void* __restrict__ Cv,
    int M, int N, int K, int lda, int ldb, int ldc,
    long long sAz, long long sBz, long long sCz,
    int maskA, int shiftB, int maskB, float alpha,
    const float* __restrict__ bias,
    const float* __restrict__ xres,
    const float* __restrict__ heat)
{
  __shared__ __align__(16) __bf16 Atile[128*32];
  __shared__ __align__(16) __bf16 Btile[128*32];

  const int tid  = threadIdx.x;
  const int lane = tid & 63;
  const int wv   = tid >> 6;
  const int wr   = wv >> 1, wc = wv & 1;
  const int n0 = blockIdx.x * 128, m0 = blockIdx.y * 128;
  const int z  = blockIdx.z;

  const __bf16* Ab = A  + (long long)(z & maskA) * sAz;
  const __bf16* Bb = Bm + (long long)((z >> shiftB) & maskB) * sBz;

  // ---- staging: per-lane global pointers (loop-carried), swizzled source kc ----
  const __bf16* gA[2]; const __bf16* gB[2];
  #pragma unroll
  for (int i = 0; i < 2; i++){
    int s   = wv*128 + i*64 + lane;       // 16B chunk slot
    int row = s >> 2;
    int kc  = (s & 3) ^ ((row >> 1) & 3); // swizzle
    int gm = m0 + row; if (gm > M-1) gm = M-1;
    int gn = n0 + row; if (gn > N-1) gn = N-1;
    gA[i] = Ab + (long long)gm * lda + kc * 8;
    gB[i] = Bb + (long long)gn * ldb + kc * 8;
  }
  __bf16* ldsA0 = &Atile[(wv*128      ) * 8];
  __bf16* ldsA1 = &Atile[(wv*128 + 64 ) * 8];
  __bf16* ldsB0 = &Btile[(wv*128      ) * 8];
  __bf16* ldsB1 = &Btile[(wv*128 + 64 ) * 8];

  // ---- fragment read pointers (precomputed, swizzled) ----
  const int fm = lane & 31;        // row within 32-tile
  const int kq = lane >> 5;        // 8-elem half of K=16
  const int sw = (fm >> 1) & 3;
  const __bf16* pA[2][2]; const __bf16* pB[2][2];
  #pragma unroll
  for (int rr = 0; rr < 2; rr++)
    #pragma unroll
    for (int kh = 0; kh < 2; kh++){
      int rowA = wr*64 + rr*32 + fm;
      int rowB = wc*64 + rr*32 + fm;
      pA[rr][kh] = &Atile[(rowA*4 + ((kh*2 + kq) ^ sw)) * 8];
      pB[rr][kh] = &Btile[(rowB*4 + ((kh*2 + kq) ^ sw)) * 8];
    }

  f32x16 acc[2][2] = {};

  for (int k0 = 0; k0 < K; k0 += 32){
    __syncthreads();
    async16(gA[0], ldsA0); async16(gA[1], ldsA1);
    async16(gB[0], ldsB0); async16(gB[1], ldsB1);
    gA[0] += 32; gA[1] += 32; gB[0] += 32; gB[1] += 32;
    __syncthreads();
    bf16x8 af[2][2], bfv[2][2];
    #pragma unroll
    for (int rr = 0; rr < 2; rr++)
      #pragma unroll
      for (int kh = 0; kh < 2; kh++){
        af [rr][kh] = *(const bf16x8*)pA[rr][kh];
        bfv[rr][kh] = *(const bf16x8*)pB[rr][kh];
      }
    #pragma unroll
    for (int r = 0; r < 2; r++)
      #pragma unroll
      for (int c = 0; c < 2; c++){
        acc[r][c] = __builtin_amdgcn_mfma_f32_32x32x16_bf16(af[r][0], bfv[c][0], acc[r][c], 0, 0, 0);
        acc[r][c] = __builtin_amdgcn_mfma_f32_32x32x16_bf16(af[r][1], bfv[c][1], acc[r][c], 0, 0, 0);
      }
  }

  // ---- epilogue: C/D layout col=lane&31, row=(reg&3)+8*(reg>>2)+4*(lane>>5) ----
  const int col_l = lane & 31;
  const int row_q = (lane >> 5) * 4;
  #pragma unroll
  for (int r = 0; r < 2; r++){
    #pragma unroll
    for (int c = 0; c < 2; c++){
      int gn  = n0 + wc*64 + c*32 + col_l;
      if (gn >= N) continue;
      int gmb = m0 + wr*64 + r*32 + row_q;
      f32x16 v = acc[r][c];
      #pragma unroll
      for (int g = 0; g < 4; g++){
        #pragma unroll
        for (int q = 0; q < 4; q++){
          int gm = gmb + g*8 + q;
          if (gm >= M) continue;
          float cval = alpha * v[g*4 + q];
          long long cidx = (long long)z*sCz + (long long)gm*ldc + gn;
          if (EPI == 1){
            ((__hip_bfloat16*)Cv)[cidx] = __float2bfloat16(cval);
          } else if (EPI == 2){
            float h = cval + bias[gn];
            float ge = 0.5f * h * (1.f + erff(h * 0.70710678118654752f));
            ((__hip_bfloat16*)Cv)[cidx] = __float2bfloat16(ge);
          } else {
            float h = cval + bias[gn];
            int bq = gm / NP1;
            int rr2 = gm - bq * NP1;
            float f = (rr2 == 0) ? 1.f : heat[bq*NTOK + (rr2 - 1)];
            ((float*)Cv)[cidx] = xres[cidx] + f * h;
          }
        }
      }
    }
  }
}

extern "C" void kernel_launch(void* const* d_in, const int* in_sizes, int n_in,
                              void* d_out, int out_size, void* d_ws, size_t ws_size,
                              hipStream_t stream)
{
  const float* x       = (const float*)d_in[0];
  const float* y       = (const float*)d_in[1];
  const float* coords  = (const float*)d_in[2];
  const float* U       = (const float*)d_in[3];
  const float* S1      = (const float*)d_in[4];
  const float* S2      = (const float*)d_in[5];
  const float* gating  = (const float*)d_in[6];
  const float* h_temp  = (const float*)d_in[7];
  const float* p_temp  = (const float*)d_in[8];
  const float* pos_emb = (const float*)d_in[9];
  const float* W1      = (const float*)d_in[10];
  const float* b1      = (const float*)d_in[11];
  const float* W2      = (const float*)d_in[12];
  const float* b2      = (const float*)d_in[13];
  float* out = (float*)d_out;
  char* ws = (char*)d_ws;

  size_t off = 0;
  auto alloc = [&](size_t bytes){ size_t r = off; off = (off + bytes + 255) & ~(size_t)255; return r; };
  const long long NN  = (long long)NTOK * NTOK;
  const long long DD  = (long long)DIM * DIM;
  const size_t o_pos  = alloc(NN * 4);                       // pos fp32
  const size_t o_S    = alloc((size_t)BB*NP1*DFF * 2);       // hg bf16 region; S bf16 (32MB) overlays start
  const size_t o_xy   = alloc((size_t)BB*NP1*1536 * 2);      // xy bf16
  const size_t o_yb   = alloc((size_t)BB*NTOK*DIM * 2);      // yb bf16
  const size_t o_ybT  = alloc((size_t)BB*DIM*NTOK * 2);      // ybT bf16
  const size_t o_xs   = alloc((size_t)2*BB*NTOK*DIM * 2);    // xs bf16 (k,b,N,D)
  const size_t o_attn = alloc((size_t)BB*NN * 2);            // attnc bf16
  const size_t o_UT   = alloc((size_t)DD * 2);
  const size_t o_UTs  = alloc((size_t)2*DD * 2);             // UTs1,UTs2
  const size_t o_Mk   = alloc((size_t)2*DD * 2);             // M1,M2 bf16
  const size_t o_W1T  = alloc((size_t)DFF*2*DIM * 2);
  const size_t o_W2T  = alloc((size_t)DIM*DFF * 2);
  const size_t o_heat = alloc((size_t)BB*NTOK * 4);

  __hip_bfloat16* S_bf = (__hip_bfloat16*)(ws + o_S);        // (2,B,N,N) bf16
  __hip_bfloat16* hg   = (__hip_bfloat16*)(ws + o_S);        // overlay (post-rowproc)
  __hip_bfloat16* xy   = (__hip_bfloat16*)(ws + o_xy);
  __hip_bfloat16* yb   = (__hip_bfloat16*)(ws + o_yb);
  __hip_bfloat16* ybT  = (__hip_bfloat16*)(ws + o_ybT);
  __hip_bfloat16* xs   = (__hip_bfloat16*)(ws + o_xs);
  __hip_bfloat16* attnc= (__hip_bfloat16*)(ws + o_attn);
  __hip_bfloat16* UT   = (__hip_bfloat16*)(ws + o_UT);
  __hip_bfloat16* UTs  = (__hip_bfloat16*)(ws + o_UTs);
  __hip_bfloat16* Mk   = (__hip_bfloat16*)(ws + o_Mk);
  __hip_bfloat16* W1T  = (__hip_bfloat16*)(ws + o_W1T);
  __hip_bfloat16* W2T  = (__hip_bfloat16*)(ws + o_W2T);
  float* pos  = (float*)(ws + o_pos);
  float* heat = (float*)(ws + o_heat);

  const float scale = 0.03608439182435161f; // 768^-0.5
  dim3 blk(256);

  // ---- prep ----
  pos_kernel<<<dim3(NTOK), blk, 0, stream>>>(coords, pos_emb, p_temp, pos);
  conv_xy_kernel<<<dim3((BB*NP1*DIM)/256), blk, 0, stream>>>(x, y, xy);
  transpose_conv_kernel<<<dim3(DIM/32, DIM/32, 1), blk, 0, stream>>>(
      U, 0LL, DIM, UT, 0LL, nullptr, 0LL, DIM, DIM, S1, S2, UTs, UTs + DD);
  transpose_conv_kernel<<<dim3(DFF/32, (2*DIM)/32, 1), blk, 0, stream>>>(
      W1, 0LL, DFF, W1T, 0LL, nullptr, 0LL, 2*DIM, DFF, nullptr, nullptr, nullptr, nullptr);
  transpose_conv_kernel<<<dim3(DIM/32, DFF/32, 1), blk, 0, stream>>>(
      W2, 0LL, DIM, W2T, 0LL, nullptr, 0LL, DFF, DIM, nullptr, nullptr, nullptr, nullptr);
  transpose_conv_kernel<<<dim3(DIM/32, NTOK/32, BB), blk, 0, stream>>>(
      y + DIM, (long long)NP1*DIM, DIM, ybT, (long long)DIM*NTOK, yb, (long long)NTOK*DIM,
      NTOK, DIM, nullptr, nullptr, nullptr, nullptr);

  // ---- G1: M_k = UT @ UTs_k^T (symmetric), z=2 ----
  mfma_gemm<1><<<dim3(DIM/128, DIM/128, 2), blk, 0, stream>>>(
      (const __bf16*)UT, (const __bf16*)UTs, Mk,
      DIM, DIM, DIM, DIM, DIM, DIM,
      0LL, DD, DD, 0, 0, 1, 1.f, nullptr, nullptr, nullptr);

  // ---- G2: xs[k,b] = xb[b] @ M_k^T, z=k*8+b ----
  mfma_gemm<1><<<dim3(DIM/128, NTOK/128, 16), blk, 0, stream>>>(
      (const __bf16*)(xy + 1536), (const __bf16*)Mk, xs,
      NTOK, DIM, DIM, 1536, DIM, DIM,
      (long long)NP1*1536, DD, (long long)NTOK*DIM,
      7, 3, 1, 1.f, nullptr, nullptr, nullptr);

  // ---- G3: S[k,b] = bf16( scale * xs[k,b] @ yb[b]^T ) ----
  mfma_gemm<1><<<dim3(NTOK/128, NTOK/128, 16), blk, 0, stream>>>(
      (const __bf16*)xs, (const __bf16*)yb, S_bf,
      NTOK, NTOK, DIM, DIM, DIM, NTOK,
      (long long)NTOK*DIM, (long long)NTOK*DIM, NN,
      15, 0, 7, scale, nullptr, nullptr, nullptr);

  // ---- rowproc: softmax + mix + entropy + select ----
  rowproc_kernel<<<dim3(BB*NTOK), blk, 0, stream>>>(S_bf, pos, attnc, heat, gating, h_temp);

  // ---- G4: y_out[b] = attnc[b] @ ybT[b]^T -> xy cols 768.., rows 1.. ----
  mfma_gemm<1><<<dim3(DIM/128, NTOK/128, BB), blk, 0, stream>>>(
      (const __bf16*)attnc, (const __bf16*)ybT, xy + 1536 + DIM,
      NTOK, DIM, NTOK, NTOK, NTOK, 1536,
      NN, (long long)DIM*NTOK, (long long)NP1*1536,
      7, 0, 7, 1.f, nullptr, nullptr, nullptr);

  // ---- G5: hg = gelu(xy @ W1T^T + b1), flattened M=8200 ----
  mfma_gemm<2><<<dim3(DFF/128, (BB*NP1 + 127)/128, 1), blk, 0, stream>>>(
      (const __bf16*)xy, (const __bf16*)W1T, hg,
      BB*NP1, DFF, 2*DIM, 1536, 1536, DFF,
      0LL, 0LL, 0LL, 0, 0, 0, 1.f, b1, nullptr, nullptr);

  // ---- G6: out = x + heatrow*(hg @ W2T^T + b2), flattened M=8200 ----
  mfma_gemm<3><<<dim3(DIM/128, (BB*NP1 + 127)/128, 1), blk, 0, stream>>>(
      (const __bf16*)hg, (const __bf16*)W2T, out,
      BB*NP1, DIM, DFF, DFF, DFF, DIM,
      0LL, 0LL, 0LL, 0, 0, 0, 1.f, b2, x, heat);
}

// Round 5
// 540.156 us; speedup vs baseline: 7.9521x; 1.0719x over previous
//
#include <hip/hip_runtime.h>
#include <hip/hip_bf16.h>
#include <math.h>

#define BB   8
#define NTOK 1024
#define DIM  768
#define DFF  3072
#define NP1  1025

typedef __bf16 bf16x8 __attribute__((ext_vector_type(8)));
typedef float  f32x4  __attribute__((ext_vector_type(4)));
typedef float  f32x16 __attribute__((ext_vector_type(16)));

// ---------------- reductions (wave = 64) ----------------
__device__ __forceinline__ float waveMax(float v){
  #pragma unroll
  for (int o = 32; o > 0; o >>= 1) v = fmaxf(v, __shfl_down(v, o, 64));
  return v;
}
__device__ __forceinline__ float waveSum(float v){
  #pragma unroll
  for (int o = 32; o > 0; o >>= 1) v += __shfl_down(v, o, 64);
  return v;
}
__device__ __forceinline__ float blockMax(float v, float* red){
  int lane = threadIdx.x & 63, w = threadIdx.x >> 6;
  v = waveMax(v);
  if (lane == 0) red[w] = v;
  __syncthreads();
  float r = fmaxf(fmaxf(red[0], red[1]), fmaxf(red[2], red[3]));
  __syncthreads();
  return r;
}
__device__ __forceinline__ float blockSum(float v, float* red){
  int lane = threadIdx.x & 63, w = threadIdx.x >> 6;
  v = waveSum(v);
  if (lane == 0) red[w] = v;
  __syncthreads();
  float r = red[0] + red[1] + red[2] + red[3];
  __syncthreads();
  return r;
}

// ---------------- pos softmax ----------------
__global__ __launch_bounds__(256) void pos_kernel(
    const float* __restrict__ coords, const float* __restrict__ pos_emb,
    const float* __restrict__ p_temp, float* __restrict__ pos)
{
  int i = blockIdx.x;
  int tid = threadIdx.x;
  __shared__ float red[4];
  __shared__ float pe[6];
  if (tid < 6) pe[tid] = pos_emb[i*6 + tid];
  __syncthreads();
  float pt = fabsf(p_temp[0]);
  float v[4]; float mx = -INFINITY;
  #pragma unroll
  for (int j = 0; j < 4; j++){
    int jj = tid + j*256;
    const float* c = coords + ((long long)i*NTOK + jj)*6;
    float d = c[0]*pe[0] + c[1]*pe[1] + c[2]*pe[2] + c[3]*pe[3] + c[4]*pe[4] + c[5]*pe[5];
    v[j] = -pt * d;
    mx = fmaxf(mx, v[j]);
  }
  mx = blockMax(mx, red);
  float s = 0.f;
  #pragma unroll
  for (int j = 0; j < 4; j++){ v[j] = __expf(v[j] - mx); s += v[j]; }
  s = blockSum(s, red);
  float inv = 1.f / s;
  #pragma unroll
  for (int j = 0; j < 4; j++) pos[(long long)i*NTOK + tid + j*256] = v[j] * inv;
}

// ------- per-row: softmax(S bf16) -> attn -> entropy -> select -> attnc bf16, heat ----
__global__ __launch_bounds__(256) void rowproc_kernel(
    const __hip_bfloat16* __restrict__ S,
    const float* __restrict__ pos,
    __hip_bfloat16* __restrict__ attnc, // (B,N,N)
    float* __restrict__ heat,           // (B,N)
    const float* __restrict__ gating, const float* __restrict__ h_temp)
{
  int row = blockIdx.x;           // b*N + i
  int b = row >> 10, i = row & 1023;
  int tid = threadIdx.x;
  __shared__ __align__(16) float a0[NTOK];
  __shared__ __align__(16) float a1[NTOK];
  __shared__ float red[4];
  float g = 1.f / (1.f + __expf(-gating[0]));
  float ht = h_temp[0];
  float ent[2];
  const int c0 = tid * 4;
  f32x4 pv = *(const f32x4*)&pos[(long long)i*NTOK + c0];
  #pragma unroll
  for (int k = 0; k < 2; k++){
    const __hip_bfloat16* Sr = S + ((long long)((k*8 + b)*NTOK) + i) * NTOK;
    union { uint2 u; __hip_bfloat16 h[4]; } ld;
    ld.u = *(const uint2*)&Sr[c0];
    f32x4 v;
    #pragma unroll
    for (int j = 0; j < 4; j++) v[j] = __bfloat162float(ld.h[j]);
    float mx = fmaxf(fmaxf(v[0], v[1]), fmaxf(v[2], v[3]));
    mx = blockMax(mx, red);
    float s = 0.f;
    #pragma unroll
    for (int j = 0; j < 4; j++){ v[j] = __expf(v[j] - mx); s += v[j]; }
    s = blockSum(s, red);
    float inv = 1.f / s;
    float e = 0.f;
    float* arow = k ? a1 : a0;
    f32x4 at;
    #pragma unroll
    for (int j = 0; j < 4; j++){
      at[j] = (1.f - g) * (v[j] * inv) + g * pv[j];
      e += -at[j] * __logf(at[j] + 1e-8f);
    }
    *(f32x4*)&arow[c0] = at;
    ent[k] = blockSum(e, red);
  }
  float h0 = 2.f - 2.f / (1.f + __expf(-ht * ent[0]));
  float h1 = 2.f - 2.f / (1.f + __expf(-ht * ent[1]));
  bool fg = (h0 >= h1);
  if (tid == 0) heat[row] = fg ? h0 : h1;
  const float* sel = fg ? a0 : a1;
  f32x4 sv = *(const f32x4*)&sel[c0];
  union { __hip_bfloat16 h[4]; uint2 u; } pk;
  #pragma unroll
  for (int j = 0; j < 4; j++) pk.h[j] = __float2bfloat16(sv[j]);
  *(uint2*)(attnc + ((long long)b*NTOK + i)*NTOK + c0) = pk.u;
}

// ---------------- x,y -> xy bf16 (B,1025,1536) ----------------
__global__ __launch_bounds__(256) void conv_xy_kernel(
    const float* __restrict__ x, const float* __restrict__ y, __hip_bfloat16* __restrict__ xy)
{
  long long idx = (long long)blockIdx.x*256 + threadIdx.x;   // < B*1025*768
  int d = (int)(idx % DIM);
  long long br = idx / DIM;     // b*1025 + r
  int r = (int)(br % NP1);
  xy[br*1536 + d] = __float2bfloat16(x[idx]);
  if (r == 0) xy[br*1536 + DIM + d] = __float2bfloat16(y[idx]);
}

// in fp32 [R][C] -> outT bf16 [C][R]; optional straight outS bf16 [R][C];
// optional scaled transposes outT1/outT2 (|sc1[r]|,|sc2[r]| along original row r)
__global__ __launch_bounds__(256) void transpose_conv_kernel(
    const float* __restrict__ in, long long sIn, int ldin,
    __hip_bfloat16* __restrict__ outT, long long sT,
    __hip_bfloat16* __restrict__ outS, long long sS,
    int R, int C,
    const float* __restrict__ sc1, const float* __restrict__ sc2,
    __hip_bfloat16* __restrict__ outT1, __hip_bfloat16* __restrict__ outT2)
{
  __shared__ float tile[32][33];
  int bx = blockIdx.x, by = blockIdx.y, z = blockIdx.z;
  const float* inb = in + (long long)z*sIn;
  int tx = threadIdx.x & 31, ty = threadIdx.x >> 5;
  #pragma unroll
  for (int p = 0; p < 4; p++){
    int r = by*32 + p*8 + ty;
    int c = bx*32 + tx;
    float v = inb[(long long)r*ldin + c];
    tile[p*8 + ty][tx] = v;
    if (outS) outS[(long long)z*sS + (long long)r*C + c] = __float2bfloat16(v);
  }
  __syncthreads();
  #pragma unroll
  for (int p = 0; p < 4; p++){
    int c = bx*32 + p*8 + ty;   // original col
    int r = by*32 + tx;         // original row
    float v = tile[tx][p*8 + ty];
    long long oidx = (long long)z*sT + (long long)c*R + r;
    outT[oidx] = __float2bfloat16(v);
    if (outT1) outT1[(long long)c*R + r] = __float2bfloat16(v * fabsf(sc1[r]));
    if (outT2) outT2[(long long)c*R + r] = __float2bfloat16(v * fabsf(sc2[r]));
  }
}

// ---------------- bf16 MFMA GEMM (32x32x16, BK=64), BT form ----------------
// C[z][M][N] = alpha * A[(z&maskA)][M][K] * B[(z>>shiftB)&maskB][N][K]^T  (+ epilogue)
// EPI: 1 = bf16 alpha*acc ; 2 = bf16 gelu(acc+bias) ; 3 = fp32 xres + heatrow*(acc+bias) flat rows
// LDS: 128 rows x 64 bf16 per matrix (128B row = 32 banks); 16B chunks XOR-swizzled by (row&7).
// K must be a multiple of 64.
__device__ __forceinline__ void async16(const __bf16* gp, __bf16* lp){
  __builtin_amdgcn_global_load_lds(
      (const __attribute__((address_space(1))) void*)gp,
      (__attribute__((address_space(3))) void*)lp, 16, 0, 0);
}

template<int EPI>
__global__ __launch_bounds__(256) void mfma_gemm(
    const __bf16* __restrict__ A, const __bf16* __restrict__ Bm, void* __restrict__ Cv,
    int M, int N, int K, int lda, int ldb, int ldc,
    long long sAz, long long sBz, long long sCz,
    int maskA, int shiftB, int maskB, float alpha,
    const float* __restrict__ bias,
    const float* __restrict__ xres,
    const float* __restrict__ heat)
{
  __shared__ __align__(16) __bf16 Atile[128*64];
  __shared__ __align__(16) __bf16 Btile[128*64];

  const int tid  = threadIdx.x;
  const int lane = tid & 63;
  const int wv   = tid >> 6;
  const int wr   = wv >> 1, wc = wv & 1;
  const int n0 = blockIdx.x * 128, m0 = blockIdx.y * 128;
  const int z  = blockIdx.z;

  const __bf16* Ab = A  + (long long)(z & maskA) * sAz;
  const __bf16* Bb = Bm + (long long)((z >> shiftB) & maskB) * sBz;

  // ---- staging: per-lane global pointers (loop-carried), swizzled source chunk ----
  // tile = 1024 16B-chunks; instruction i of wave wv covers chunks [(i*4+wv)*64, +64)
  const __bf16* gA[4]; const __bf16* gB[4];
  __bf16 *lA[4], *lB[4];
  #pragma unroll
  for (int i = 0; i < 4; i++){
    int s0  = (i*4 + wv) * 64;
    int s   = s0 + lane;
    int row = s >> 3;
    int kc  = (s & 7) ^ (row & 7);   // physical slot s holds global chunk kc
    int gm = m0 + row; if (gm > M-1) gm = M-1;
    int gn = n0 + row; if (gn > N-1) gn = N-1;
    gA[i] = Ab + (long long)gm * lda + kc * 8;
    gB[i] = Bb + (long long)gn * ldb + kc * 8;
    lA[i] = &Atile[s0 * 8];
    lB[i] = &Btile[s0 * 8];
  }

  // ---- fragment read pointers (precomputed, swizzled) ----
  const int fm = lane & 31;        // row within 32-tile
  const int kq = lane >> 5;        // 8-elem half of each K=16 step
  const __bf16* pA[2][4]; const __bf16* pB[2][4];
  #pragma unroll
  for (int rr = 0; rr < 2; rr++){
    int rowA = wr*64 + rr*32 + fm;
    int rowB = wc*64 + rr*32 + fm;
    #pragma unroll
    for (int st = 0; st < 4; st++){
      pA[rr][st] = &Atile[rowA*64 + ((st*2 + kq) ^ (rowA & 7)) * 8];
      pB[rr][st] = &Btile[rowB*64 + ((st*2 + kq) ^ (rowB & 7)) * 8];
    }
  }

  f32x16 acc[2][2] = {};

  for (int k0 = 0; k0 < K; k0 += 64){
    __syncthreads();
    #pragma unroll
    for (int i = 0; i < 4; i++){ async16(gA[i], lA[i]); async16(gB[i], lB[i]); }
    #pragma unroll
    for (int i = 0; i < 4; i++){ gA[i] += 64; gB[i] += 64; }
    __syncthreads();
    #pragma unroll
    for (int st = 0; st < 4; st++){
      bf16x8 a0 = *(const bf16x8*)pA[0][st];
      bf16x8 a1 = *(const bf16x8*)pA[1][st];
      bf16x8 b0 = *(const bf16x8*)pB[0][st];
      bf16x8 b1 = *(const bf16x8*)pB[1][st];
      acc[0][0] = __builtin_amdgcn_mfma_f32_32x32x16_bf16(a0, b0, acc[0][0], 0, 0, 0);
      acc[0][1] = __builtin_amdgcn_mfma_f32_32x32x16_bf16(a0, b1, acc[0][1], 0, 0, 0);
      acc[1][0] = __builtin_amdgcn_mfma_f32_32x32x16_bf16(a1, b0, acc[1][0], 0, 0, 0);
      acc[1][1] = __builtin_amdgcn_mfma_f32_32x32x16_bf16(a1, b1, acc[1][1], 0, 0, 0);
    }
  }

  // ---- epilogue: C/D layout col=lane&31, row=(reg&3)+8*(reg>>2)+4*(lane>>5) ----
  const int col_l = lane & 31;
  const int row_q = (lane >> 5) * 4;
  #pragma unroll
  for (int r = 0; r < 2; r++){
    #pragma unroll
    for (int c = 0; c < 2; c++){
      int gn  = n0 + wc*64 + c*32 + col_l;
      if (gn >= N) continue;
      int gmb = m0 + wr*64 + r*32 + row_q;
      f32x16 v = acc[r][c];
      #pragma unroll
      for (int g = 0; g < 4; g++){
        #pragma unroll
        for (int q = 0; q < 4; q++){
          int gm = gmb + g*8 + q;
          if (gm >= M) continue;
          float cval = alpha * v[g*4 + q];
          long long cidx = (long long)z*sCz + (long long)gm*ldc + gn;
          if (EPI == 1){
            ((__hip_bfloat16*)Cv)[cidx] = __float2bfloat16(cval);
          } else if (EPI == 2){
            float h = cval + bias[gn];
            float ge = 0.5f * h * (1.f + erff(h * 0.70710678118654752f));
            ((__hip_bfloat16*)Cv)[cidx] = __float2bfloat16(ge);
          } else {
            float h = cval + bias[gn];
            int bq = gm / NP1;
            int rr2 = gm - bq * NP1;
            float f = (rr2 == 0) ? 1.f : heat[bq*NTOK + (rr2 - 1)];
            ((float*)Cv)[cidx] = xres[cidx] + f * h;
          }
        }
      }
    }
  }
}

extern "C" void kernel_launch(void* const* d_in, const int* in_sizes, int n_in,
                              void* d_out, int out_size, void* d_ws, size_t ws_size,
                              hipStream_t stream)
{
  const float* x       = (const float*)d_in[0];
  const float* y       = (const float*)d_in[1];
  const float* coords  = (const float*)d_in[2];
  const float* U       = (const float*)d_in[3];
  const float* S1      = (const float*)d_in[4];
  const float* S2      = (const float*)d_in[5];
  const float* gating  = (const float*)d_in[6];
  const float* h_temp  = (const float*)d_in[7];
  const float* p_temp  = (const float*)d_in[8];
  const float* pos_emb = (const float*)d_in[9];
  const float* W1      = (const float*)d_in[10];
  const float* b1      = (const float*)d_in[11];
  const float* W2      = (const float*)d_in[12];
  const float* b2      = (const float*)d_in[13];
  float* out = (float*)d_out;
  char* ws = (char*)d_ws;

  size_t off = 0;
  auto alloc = [&](size_t bytes){ size_t r = off; off = (off + bytes + 255) & ~(size_t)255; return r; };
  const long long NN  = (long long)NTOK * NTOK;
  const long long DD  = (long long)DIM * DIM;
  const size_t o_pos  = alloc(NN * 4);                       // pos fp32
  const size_t o_S    = alloc((size_t)BB*NP1*DFF * 2);       // hg bf16 region; S bf16 (32MB) overlays start
  const size_t o_xy   = alloc((size_t)BB*NP1*1536 * 2);      // xy bf16
  const size_t o_yb   = alloc((size_t)BB*NTOK*DIM * 2);      // yb bf16
  const size_t o_ybT  = alloc((size_t)BB*DIM*NTOK * 2);      // ybT bf16
  const size_t o_xs   = alloc((size_t)2*BB*NTOK*DIM * 2);    // xs bf16 (k,b,N,D)
  const size_t o_attn = alloc((size_t)BB*NN * 2);            // attnc bf16
  const size_t o_UT   = alloc((size_t)DD * 2);
  const size_t o_UTs  = alloc((size_t)2*DD * 2);             // UTs1,UTs2
  const size_t o_Mk   = alloc((size_t)2*DD * 2);             // M1,M2 bf16
  const size_t o_W1T  = alloc((size_t)DFF*2*DIM * 2);
  const size_t o_W2T  = alloc((size_t)DIM*DFF * 2);
  const size_t o_heat = alloc((size_t)BB*NTOK * 4);

  __hip_bfloat16* S_bf = (__hip_bfloat16*)(ws + o_S);        // (2,B,N,N) bf16
  __hip_bfloat16* hg   = (__hip_bfloat16*)(ws + o_S);        // overlay (post-rowproc)
  __hip_bfloat16* xy   = (__hip_bfloat16*)(ws + o_xy);
  __hip_bfloat16* yb   = (__hip_bfloat16*)(ws + o_yb);
  __hip_bfloat16* ybT  = (__hip_bfloat16*)(ws + o_ybT);
  __hip_bfloat16* xs   = (__hip_bfloat16*)(ws + o_xs);
  __hip_bfloat16* attnc= (__hip_bfloat16*)(ws + o_attn);
  __hip_bfloat16* UT   = (__hip_bfloat16*)(ws + o_UT);
  __hip_bfloat16* UTs  = (__hip_bfloat16*)(ws + o_UTs);
  __hip_bfloat16* Mk   = (__hip_bfloat16*)(ws + o_Mk);
  __hip_bfloat16* W1T  = (__hip_bfloat16*)(ws + o_W1T);
  __hip_bfloat16* W2T  = (__hip_bfloat16*)(ws + o_W2T);
  float* pos  = (float*)(ws + o_pos);
  float* heat = (float*)(ws + o_heat);

  const float scale = 0.03608439182435161f; // 768^-0.5
  dim3 blk(256);

  // ---- prep ----
  pos_kernel<<<dim3(NTOK), blk, 0, stream>>>(coords, pos_emb, p_temp, pos);
  conv_xy_kernel<<<dim3((BB*NP1*DIM)/256), blk, 0, stream>>>(x, y, xy);
  transpose_conv_kernel<<<dim3(DIM/32, DIM/32, 1), blk, 0, stream>>>(
      U, 0LL, DIM, UT, 0LL, nullptr, 0LL, DIM, DIM, S1, S2, UTs, UTs + DD);
  transpose_conv_kernel<<<dim3(DFF/32, (2*DIM)/32, 1), blk, 0, stream>>>(
      W1, 0LL, DFF, W1T, 0LL, nullptr, 0LL, 2*DIM, DFF, nullptr, nullptr, nullptr, nullptr);
  transpose_conv_kernel<<<dim3(DIM/32, DFF/32, 1), blk, 0, stream>>>(
      W2, 0LL, DIM, W2T, 0LL, nullptr, 0LL, DFF, DIM, nullptr, nullptr, nullptr, nullptr);
  transpose_conv_kernel<<<dim3(DIM/32, NTOK/32, BB), blk, 0, stream>>>(
      y + DIM, (long long)NP1*DIM, DIM, ybT, (long long)DIM*NTOK, yb, (long long)NTOK*DIM,
      NTOK, DIM, nullptr, nullptr, nullptr, nullptr);

  // ---- G1: M_k = UT @ UTs_k^T (symmetric), z=2 ----
  mfma_gemm<1><<<dim3(DIM/128, DIM/128, 2), blk, 0, stream>>>(
      (const __bf16*)UT, (const __bf16*)UTs, Mk,
      DIM, DIM, DIM, DIM, DIM, DIM,
      0LL, DD, DD, 0, 0, 1, 1.f, nullptr, nullptr, nullptr);

  // ---- G2: xs[k,b] = xb[b] @ M_k^T, z=k*8+b ----
  mfma_gemm<1><<<dim3(DIM/128, NTOK/128, 16), blk, 0, stream>>>(
      (const __bf16*)(xy + 1536), (const __bf16*)Mk, xs,
      NTOK, DIM, DIM, 1536, DIM, DIM,
      (long long)NP1*1536, DD, (long long)NTOK*DIM,
      7, 3, 1, 1.f, nullptr, nullptr, nullptr);

  // ---- G3: S[k,b] = bf16( scale * xs[k,b] @ yb[b]^T ) ----
  mfma_gemm<1><<<dim3(NTOK/128, NTOK/128, 16), blk, 0, stream>>>(
      (const __bf16*)xs, (const __bf16*)yb, S_bf,
      NTOK, NTOK, DIM, DIM, DIM, NTOK,
      (long long)NTOK*DIM, (long long)NTOK*DIM, NN,
      15, 0, 7, scale, nullptr, nullptr, nullptr);

  // ---- rowproc: softmax + mix + entropy + select ----
  rowproc_kernel<<<dim3(BB*NTOK), blk, 0, stream>>>(S_bf, pos, attnc, heat, gating, h_temp);

  // ---- G4: y_out[b] = attnc[b] @ ybT[b]^T -> xy cols 768.., rows 1.. ----
  mfma_gemm<1><<<dim3(DIM/128, NTOK/128, BB), blk, 0, stream>>>(
      (const __bf16*)attnc, (const __bf16*)ybT, xy + 1536 + DIM,
      NTOK, DIM, NTOK, NTOK, NTOK, 1536,
      NN, (long long)DIM*NTOK, (long long)NP1*1536,
      7, 0, 7, 1.f, nullptr, nullptr, nullptr);

  // ---- G5: hg = gelu(xy @ W1T^T + b1), flattened M=8200 ----
  mfma_gemm<2><<<dim3(DFF/128, (BB*NP1 + 127)/128, 1), blk, 0, stream>>>(
      (const __bf16*)xy, (const __bf16*)W1T, hg,
      BB*NP1, DFF, 2*DIM, 1536, 1536, DFF,
      0LL, 0LL, 0LL, 0, 0, 0, 1.f, b1, nullptr, nullptr);

  // ---- G6: out = x + heatrow*(hg @ W2T^T + b2), flattened M=8200 ----
  mfma_gemm<3><<<dim3(DIM/128, (BB*NP1 + 127)/128, 1), blk, 0, stream>>>(
      (const __bf16*)hg, (const __bf16*)W2T, out,
      BB*NP1, DIM, DFF, DFF, DFF, DIM,
      0LL, 0LL, 0LL, 0, 0, 0, 1.f, b2, x, heat);
}